// Round 12
// baseline (929.314 us; speedup 1.0000x reference)
//
#include <hip/hip_runtime.h>
#include <hip/hip_bf16.h>
#include <hip/hip_cooperative_groups.h>

#define N_NODES 30000
#define N_EDGES 240000
#define ETOT    (N_EDGES + N_NODES)   // 270000 (self loops appended)
#define NGRAPH  128
#define NBLK    118                   // ceil(30000/256)

typedef __attribute__((ext_vector_type(8))) short bf16x8;
typedef __attribute__((ext_vector_type(4))) short bf16x4;
typedef __attribute__((ext_vector_type(4))) float f32x4;

__device__ __forceinline__ unsigned short f2bf(float f) {
    unsigned u = __float_as_uint(f);
    u += 0x7fff + ((u >> 16) & 1);        // round-to-nearest-even
    return (unsigned short)(u >> 16);
}
__device__ __forceinline__ float bf2f(unsigned short h) {
    return __uint_as_float(((unsigned)h) << 16);
}

// ---------- cooperative prep: weights->bf16T, x->bf16, bounds, CSR build ----------
__global__ void coop_prep(const float* __restrict__ W,
                          const float* __restrict__ Win,
                          const float* __restrict__ Wout,
                          const float* __restrict__ x,
                          const int* __restrict__ batch,
                          const int* __restrict__ ei0,
                          const int* __restrict__ ei1,
                          short* __restrict__ wt_hi,
                          short* __restrict__ wint_hi,
                          short* __restrict__ woutt_hi,
                          short* __restrict__ xb,
                          int* __restrict__ gstart,
                          int* __restrict__ deg,
                          int* __restrict__ rowptr,
                          int* __restrict__ wofs,
                          int* __restrict__ scantmp,
                          int* __restrict__ blksum,
                          int* __restrict__ blkoff,
                          int* __restrict__ csr_src,
                          float* __restrict__ bnsum) {
    cooperative_groups::grid_group grid = cooperative_groups::this_grid();
    const int gtid = blockIdx.x * 256 + threadIdx.x;
    const int gsz  = gridDim.x * 256;
    __shared__ int sh[256];

    // phase A: weight transpose->bf16, x->bf16, zero deg/bnsum, graph bounds
    for (int i = gtid; i < 294912; i += gsz) {
        if (i < 196608) {
            int l = i >> 16, r = i & 65535;
            int n = r >> 7, k = r & 127;
            wt_hi[i] = (short)f2bf(W[(size_t)l * 65536 + k * 512 + n]);
        } else if (i < 245760) {
            int j = i - 196608;
            int l = j >> 14, r = j & 16383;
            int n = r >> 7, k = r & 127;
            wint_hi[j] = (short)f2bf(Win[(size_t)l * 16384 + k * 128 + n]);
        } else {
            int j = i - 245760;
            int l = j >> 14, r = j & 16383;
            int n = r >> 7, k = r & 127;
            woutt_hi[j] = (short)f2bf(Wout[(size_t)l * 16384 + k * 128 + n]);
        }
    }
    for (int j = gtid; j < N_NODES * 16; j += gsz) {     // 8 floats each
        const float4* p = (const float4*)x + (size_t)j * 2;
        float4 v0 = p[0], v1 = p[1];
        bf16x8 hv;
        hv[0] = (short)f2bf(v0.x); hv[1] = (short)f2bf(v0.y);
        hv[2] = (short)f2bf(v0.z); hv[3] = (short)f2bf(v0.w);
        hv[4] = (short)f2bf(v1.x); hv[5] = (short)f2bf(v1.y);
        hv[6] = (short)f2bf(v1.z); hv[7] = (short)f2bf(v1.w);
        *(bf16x8*)(xb + (size_t)j * 8) = hv;
    }
    for (int i = gtid; i < N_NODES; i += gsz) deg[i] = 0;
    if (gtid < 768) bnsum[gtid] = 0.f;
    if (gtid <= NGRAPH) {
        int lo = 0, hi = N_NODES;
        while (lo < hi) { int mid = (lo + hi) >> 1; if (batch[mid] < gtid) lo = mid + 1; else hi = mid; }
        gstart[gtid] = lo;
    }
    grid.sync();
    // phase B: degree histogram
    for (int e = gtid; e < ETOT; e += gsz) {
        int d = (e < N_EDGES) ? ei1[e] : (e - N_EDGES);
        atomicAdd(&deg[d], 1);
    }
    grid.sync();
    // phase C: per-block scan (blocks 0..NBLK-1)
    if (blockIdx.x < NBLK) {
        int i = blockIdx.x * 256 + threadIdx.x;
        int v = (i < N_NODES) ? deg[i] : 0;
        sh[threadIdx.x] = v;
        __syncthreads();
        int a = v;
        for (int off = 1; off < 256; off <<= 1) {
            int u = (threadIdx.x >= off) ? sh[threadIdx.x - off] : 0;
            __syncthreads();
            a += u;
            sh[threadIdx.x] = a;
            __syncthreads();
        }
        if (i < N_NODES) scantmp[i] = a - v;
        if (threadIdx.x == 255) blksum[blockIdx.x] = a;
    }
    grid.sync();
    // phase D: scan of block sums (block 0)
    if (blockIdx.x == 0) {
        int t = threadIdx.x;
        int v = (t < NBLK) ? blksum[t] : 0;
        if (t < 128) sh[t] = v;
        __syncthreads();
        int a = v;
        for (int off = 1; off < 128; off <<= 1) {
            int u = (t >= off && t < 128) ? sh[t - off] : 0;
            __syncthreads();
            if (t < 128) { a += u; sh[t] = a; }
            __syncthreads();
        }
        if (t < NBLK) blkoff[t] = a - v;
    }
    grid.sync();
    // phase E: combine -> rowptr/wofs
    if (blockIdx.x < NBLK) {
        int i = blockIdx.x * 256 + threadIdx.x;
        if (i < N_NODES) {
            int r = scantmp[i] + blkoff[blockIdx.x];
            rowptr[i] = r;
            wofs[i]   = r;
        }
    }
    if (gtid == 0) rowptr[N_NODES] = ETOT;
    grid.sync();
    // phase F: scatter
    for (int e = gtid; e < ETOT; e += gsz) {
        int s = (e < N_EDGES) ? ei0[e] : (e - N_EDGES);
        int d = (e < N_EDGES) ? ei1[e] : (e - N_EDGES);
        int pos = atomicAdd(&wofs[d], 1);
        csr_src[pos] = s;
    }
}

// ---------- conv GEMM (bf16 x bf16) + logits + coalesced store (layer 0 only) ----
__global__ __launch_bounds__(256) void gemm_conv(const short* __restrict__ Ab,
                                                 const short* __restrict__ Bth,
                                                 const float* __restrict__ att_s,
                                                 const float* __restrict__ att_d,
                                                 unsigned short* __restrict__ hfullb,
                                                 float* __restrict__ als,
                                                 float* __restrict__ ald) {
    __shared__ short As_h[64 * 136];
    __shared__ float red_s[2][64], red_d[2][64];
    const int bm = blockIdx.x * 64;
    const int hd = blockIdx.y;
    const int bn = hd * 128;
    const int t  = threadIdx.x;
#pragma unroll
    for (int i = 0; i < 4; i++) {
        int idx8 = t + i * 256;
        int row = idx8 >> 4, c8 = (idx8 & 15) << 3;
        bf16x8 vh = {};
        if (bm + row < N_NODES)
            vh = *(const bf16x8*)(Ab + (size_t)(bm + row) * 128 + c8);
        *(bf16x8*)(As_h + row * 136 + c8) = vh;
    }
    __syncthreads();

    const int w = t >> 6, lane = t & 63;
    const int wr = w >> 1, wc = w & 1;
    const int lr = lane & 15, lg = lane >> 4;
    f32x4 acc[2][4] = {};
    const size_t bofs0 = (size_t)(bn + wc * 64 + lr) * 128 + lg * 8;
#pragma unroll
    for (int kk = 0; kk < 4; kk++) {
        bf16x8 ah[2], bh[4];
#pragma unroll
        for (int ni = 0; ni < 4; ni++) {
            size_t o = bofs0 + (size_t)ni * 16 * 128 + kk * 32;
            bh[ni] = *(const bf16x8*)(Bth + o);
        }
        int ko = kk * 32 + lg * 8;
#pragma unroll
        for (int mi = 0; mi < 2; mi++) {
            int r = wr * 32 + mi * 16 + lr;
            ah[mi] = *(const bf16x8*)(As_h + r * 136 + ko);
        }
#pragma unroll
        for (int mi = 0; mi < 2; mi++)
#pragma unroll
            for (int ni = 0; ni < 4; ni++)
                acc[mi][ni] = __builtin_amdgcn_mfma_f32_16x16x32_bf16(ah[mi], bh[ni], acc[mi][ni], 0, 0, 0);
    }
    float as_c[4], ad_c[4];
#pragma unroll
    for (int ni = 0; ni < 4; ni++) {
        int cc = wc * 64 + ni * 16 + lr;
        as_c[ni] = att_s[hd * 128 + cc];
        ad_c[ni] = att_d[hd * 128 + cc];
    }
#pragma unroll
    for (int mi = 0; mi < 2; mi++) {
#pragma unroll
        for (int r = 0; r < 4; r++) {
            float ps = 0.f, pd = 0.f;
#pragma unroll
            for (int ni = 0; ni < 4; ni++) {
                ps = fmaf(acc[mi][ni][r], as_c[ni], ps);
                pd = fmaf(acc[mi][ni][r], ad_c[ni], pd);
            }
#pragma unroll
            for (int off = 1; off < 16; off <<= 1) {
                ps += __shfl_xor(ps, off);
                pd += __shfl_xor(pd, off);
            }
            if (lr == 0) {
                int row = wr * 32 + mi * 16 + lg * 4 + r;
                red_s[wc][row] = ps;
                red_d[wc][row] = pd;
            }
        }
    }
    __syncthreads();
#pragma unroll
    for (int mi = 0; mi < 2; mi++)
#pragma unroll
        for (int ni = 0; ni < 4; ni++) {
            int nl = wc * 64 + ni * 16 + lr;
#pragma unroll
            for (int r = 0; r < 4; r++) {
                int row = wr * 32 + mi * 16 + lg * 4 + r;
                As_h[row * 136 + nl] = (short)f2bf(acc[mi][ni][r]);
            }
        }
    if (t < 64) {
        int m = bm + t;
        if (m < N_NODES) als[m * 4 + hd] = red_s[0][t] + red_s[1][t];
    } else if (t < 128) {
        int tt = t - 64;
        int m = bm + tt;
        if (m < N_NODES) ald[m * 4 + hd] = red_d[0][tt] + red_d[1][tt];
    }
    __syncthreads();
#pragma unroll
    for (int i2 = 0; i2 < 4; i2++) {
        int idx8 = t + i2 * 256;
        int row = idx8 >> 4, c8 = (idx8 & 15) << 3;
        int m = bm + row;
        if (m < N_NODES)
            *(bf16x8*)(hfullb + (size_t)m * 512 + bn + c8) = *(const bf16x8*)(As_h + row * 136 + c8);
    }
}

// ---------- fused skip(l) + conv(l+1): one 64-row block does both ----------
__global__ __launch_bounds__(256) void skip_conv(const short* __restrict__ hinb,
                                                 const float* __restrict__ g,
                                                 const float* __restrict__ bnsum,
                                                 const float* __restrict__ gamma,
                                                 const float* __restrict__ beta,
                                                 const short* __restrict__ w1h,
                                                 const short* __restrict__ w2h,
                                                 const float* __restrict__ bin,
                                                 const float* __restrict__ bout,
                                                 const short* __restrict__ wtn,    // conv W^T (l+1) [512][128]
                                                 const float* __restrict__ att_s,  // (l+1)
                                                 const float* __restrict__ att_d,
                                                 short* __restrict__ houtb,
                                                 unsigned short* __restrict__ hfullb,
                                                 float* __restrict__ als,
                                                 float* __restrict__ ald) {
    __shared__ short A1h[64 * 136], A2h[64 * 136];
    __shared__ float bnp_s[256];
    __shared__ float redS[4][64], redD[4][64];
    const int bm = blockIdx.x * 64;
    const int t  = threadIdx.x;
    if (t < 128) {
        float inv = 1.f / (float)N_NODES;
        float mu  = bnsum[t] * inv;
        float var = bnsum[128 + t] * inv - mu * mu;
        float rs  = rsqrtf(var + 1e-5f);
        float sc  = gamma[t] * rs;
        bnp_s[t]       = sc;
        bnp_s[128 + t] = beta[t] - mu * sc;
    }
    __syncthreads();
    // A1: bf16 hin tile; A2: bn(g) rounded to bf16 (MFMA operand only)
#pragma unroll
    for (int i = 0; i < 4; i++) {
        int idx8 = t + i * 256;
        int row = idx8 >> 4, c8 = (idx8 & 15) << 3;
        bf16x8 vh = {};
        if (bm + row < N_NODES)
            vh = *(const bf16x8*)(hinb + (size_t)(bm + row) * 128 + c8);
        *(bf16x8*)(A1h + row * 136 + c8) = vh;
    }
#pragma unroll
    for (int i = 0; i < 8; i++) {
        int idx4 = t + i * 256;
        int row = idx4 >> 5, c4 = (idx4 & 31) << 2;
        float4 v2 = make_float4(0.f, 0.f, 0.f, 0.f);
        if (bm + row < N_NODES) {
            float4 gv = *(const float4*)(g + (size_t)(bm + row) * 128 + c4);
            v2.x = fmaf(bnp_s[c4 + 0], gv.x, bnp_s[128 + c4 + 0]);
            v2.y = fmaf(bnp_s[c4 + 1], gv.y, bnp_s[128 + c4 + 1]);
            v2.z = fmaf(bnp_s[c4 + 2], gv.z, bnp_s[128 + c4 + 2]);
            v2.w = fmaf(bnp_s[c4 + 3], gv.w, bnp_s[128 + c4 + 3]);
        }
        *(bf16x4*)(A2h + row * 136 + c4) = (bf16x4){(short)f2bf(v2.x), (short)f2bf(v2.y),
                                                    (short)f2bf(v2.z), (short)f2bf(v2.w)};
    }
    __syncthreads();

    const int w = t >> 6, lane = t & 63;
    const int wr = w >> 1, wc = w & 1;
    const int lr = lane & 15, lg = lane >> 4;

    // phase A: P = hin@W1 + bn(g)@W2 over full 64x128; gate+relu
    {
        f32x4 acc[2][4] = {};
        const size_t bo = (size_t)(wc * 64 + lr) * 128 + lg * 8;
#pragma unroll
        for (int kk = 0; kk < 4; kk++) {
            bf16x8 a1[2], a2[2], b1[4], b2[4];
#pragma unroll
            for (int ni = 0; ni < 4; ni++) {
                size_t o = bo + (size_t)ni * 2048 + kk * 32;
                b1[ni] = *(const bf16x8*)(w1h + o);
                b2[ni] = *(const bf16x8*)(w2h + o);
            }
            int ko = kk * 32 + lg * 8;
#pragma unroll
            for (int mi = 0; mi < 2; mi++) {
                int r = wr * 32 + mi * 16 + lr;
                a1[mi] = *(const bf16x8*)(A1h + r * 136 + ko);
                a2[mi] = *(const bf16x8*)(A2h + r * 136 + ko);
            }
#pragma unroll
            for (int mi = 0; mi < 2; mi++)
#pragma unroll
                for (int ni = 0; ni < 4; ni++) {
                    acc[mi][ni] = __builtin_amdgcn_mfma_f32_16x16x32_bf16(a1[mi], b1[ni], acc[mi][ni], 0, 0, 0);
                    acc[mi][ni] = __builtin_amdgcn_mfma_f32_16x16x32_bf16(a2[mi], b2[ni], acc[mi][ni], 0, 0, 0);
                }
        }
        // gate + relu (hbn from fp32 g; hv from bf16 state = exact)
#pragma unroll
        for (int mi = 0; mi < 2; mi++)
#pragma unroll
            for (int ni = 0; ni < 4; ni++) {
                int n = wc * 64 + ni * 16 + lr;
                float bsum = bin[n] + bout[n];
                float sc = bnp_s[n], shb = bnp_s[128 + n];
#pragma unroll
                for (int r = 0; r < 4; r++) {
                    int lrow = wr * 32 + mi * 16 + lg * 4 + r;
                    int m = bm + lrow;
                    float gv = (m < N_NODES) ? g[(size_t)m * 128 + n] : 0.f;
                    float hbnv = fmaf(sc, gv, shb);
                    float hv   = bf2f((unsigned short)A1h[lrow * 136 + n]);
                    float gt   = 1.f / (1.f + __expf(-(acc[mi][ni][r] + bsum)));
                    acc[mi][ni][r] = fmaxf(gt * hbnv + (1.f - gt) * hv, 0.f);
                }
            }
        __syncthreads();          // A tiles dead
        // stage hout (bf16) into A1h
#pragma unroll
        for (int mi = 0; mi < 2; mi++)
#pragma unroll
            for (int ni = 0; ni < 4; ni++) {
                int n = wc * 64 + ni * 16 + lr;
#pragma unroll
                for (int r = 0; r < 4; r++) {
                    int lrow = wr * 32 + mi * 16 + lg * 4 + r;
                    A1h[lrow * 136 + n] = (short)f2bf(acc[mi][ni][r]);
                }
            }
        __syncthreads();
        // coalesced houtb store (64x128)
#pragma unroll
        for (int i2 = 0; i2 < 4; i2++) {
            int idx8 = t + i2 * 256;
            int row = idx8 >> 4, c8 = (idx8 & 15) << 3;
            int m = bm + row;
            if (m < N_NODES)
                *(bf16x8*)(houtb + (size_t)m * 128 + c8) = *(const bf16x8*)(A1h + row * 136 + c8);
        }
    }

    // phase B: conv(l+1) on hout tile in A1h; wave = head
    f32x4 c2[4][8] = {};
    const int hd = w;
    const size_t bo2 = (size_t)(hd * 128 + lr) * 128 + lg * 8;
#pragma unroll
    for (int kk = 0; kk < 4; kk++) {
        bf16x8 ah2[4], bh2[8];
#pragma unroll
        for (int ni = 0; ni < 8; ni++)
            bh2[ni] = *(const bf16x8*)(wtn + bo2 + (size_t)ni * 2048 + kk * 32);
        int ko = kk * 32 + lg * 8;
#pragma unroll
        for (int mi = 0; mi < 4; mi++)
            ah2[mi] = *(const bf16x8*)(A1h + (mi * 16 + lr) * 136 + ko);
#pragma unroll
        for (int mi = 0; mi < 4; mi++)
#pragma unroll
            for (int ni = 0; ni < 8; ni++)
                c2[mi][ni] = __builtin_amdgcn_mfma_f32_16x16x32_bf16(ah2[mi], bh2[ni], c2[mi][ni], 0, 0, 0);
    }
    // logits for head hd (full 128-col sum within wave)
    {
        float asc[8], adc[8];
#pragma unroll
        for (int ni = 0; ni < 8; ni++) {
            int cc = ni * 16 + lr;
            asc[ni] = att_s[hd * 128 + cc];
            adc[ni] = att_d[hd * 128 + cc];
        }
#pragma unroll
        for (int mi = 0; mi < 4; mi++)
#pragma unroll
            for (int r = 0; r < 4; r++) {
                float ps = 0.f, pd = 0.f;
#pragma unroll
                for (int ni = 0; ni < 8; ni++) {
                    ps = fmaf(c2[mi][ni][r], asc[ni], ps);
                    pd = fmaf(c2[mi][ni][r], adc[ni], pd);
                }
#pragma unroll
                for (int off = 1; off < 16; off <<= 1) {
                    ps += __shfl_xor(ps, off);
                    pd += __shfl_xor(pd, off);
                }
                if (lr == 0) {
                    int row = mi * 16 + lg * 4 + r;
                    redS[hd][row] = ps;
                    redD[hd][row] = pd;
                }
            }
    }
    __syncthreads();              // MFMAs + red writes done; A1h/A2h free
    // round 0: waves 0,1 stage heads 0,1
    if (w < 2) {
        short* dst = (w == 0) ? A1h : A2h;
#pragma unroll
        for (int mi = 0; mi < 4; mi++)
#pragma unroll
            for (int ni = 0; ni < 8; ni++)
#pragma unroll
                for (int r = 0; r < 4; r++)
                    dst[(mi * 16 + lg * 4 + r) * 136 + ni * 16 + lr] = (short)f2bf(c2[mi][ni][r]);
    }
    // als/ald (4 heads x 64 rows; redS/redD synced above)
    {
        int hd2 = t >> 6, row = t & 63;
        int m = bm + row;
        if (m < N_NODES) {
            als[m * 4 + hd2] = redS[hd2][row];
            ald[m * 4 + hd2] = redD[hd2][row];
        }
    }
    __syncthreads();
    // store heads 0,1 (cols 0..255)
#pragma unroll
    for (int it = 0; it < 8; it++) {
        int idx = t + it * 256;
        int row = idx >> 5, c8 = (idx & 31) << 3;
        int m = bm + row;
        if (m < N_NODES) {
            const short* src = (c8 < 128) ? A1h : A2h;
            *(bf16x8*)(hfullb + (size_t)m * 512 + c8) = *(const bf16x8*)(src + row * 136 + (c8 & 127));
        }
    }
    __syncthreads();
    // round 1: waves 2,3 stage heads 2,3
    if (w >= 2) {
        short* dst = (w == 2) ? A1h : A2h;
#pragma unroll
        for (int mi = 0; mi < 4; mi++)
#pragma unroll
            for (int ni = 0; ni < 8; ni++)
#pragma unroll
                for (int r = 0; r < 4; r++)
                    dst[(mi * 16 + lg * 4 + r) * 136 + ni * 16 + lr] = (short)f2bf(c2[mi][ni][r]);
    }
    __syncthreads();
#pragma unroll
    for (int it = 0; it < 8; it++) {
        int idx = t + it * 256;
        int row = idx >> 5, c8 = (idx & 31) << 3;
        int m = bm + row;
        if (m < N_NODES) {
            const short* src = (c8 < 128) ? A1h : A2h;
            *(bf16x8*)(hfullb + (size_t)m * 512 + 256 + c8) = *(const bf16x8*)(src + row * 136 + (c8 & 127));
        }
    }
}

// ---------- plain skip (last layer) ----------
__global__ __launch_bounds__(256) void skip_gate(const short* __restrict__ hinb,
                                                 const float* __restrict__ g,
                                                 const float* __restrict__ bnsum,
                                                 const float* __restrict__ gamma,
                                                 const float* __restrict__ beta,
                                                 const short* __restrict__ w1h,
                                                 const short* __restrict__ w2h,
                                                 const float* __restrict__ bin, const float* __restrict__ bout,
                                                 short* __restrict__ houtb) {
    __shared__ short A1h[64 * 136], A2h[64 * 136], A2l[64 * 136];
    __shared__ float bnp_s[256];
    const int bm = blockIdx.x * 64;
    const int bn = blockIdx.y * 64;
    const int t  = threadIdx.x;
    if (t < 128) {
        float inv = 1.f / (float)N_NODES;
        float mu  = bnsum[t] * inv;
        float var = bnsum[128 + t] * inv - mu * mu;
        float rs  = rsqrtf(var + 1e-5f);
        float sc  = gamma[t] * rs;
        bnp_s[t]       = sc;
        bnp_s[128 + t] = beta[t] - mu * sc;
    }
    __syncthreads();
#pragma unroll
    for (int i = 0; i < 4; i++) {
        int idx8 = t + i * 256;
        int row = idx8 >> 4, c8 = (idx8 & 15) << 3;
        bf16x8 vh = {};
        if (bm + row < N_NODES)
            vh = *(const bf16x8*)(hinb + (size_t)(bm + row) * 128 + c8);
        *(bf16x8*)(A1h + row * 136 + c8) = vh;
    }
#pragma unroll
    for (int i = 0; i < 8; i++) {
        int idx4 = t + i * 256;
        int row = idx4 >> 5, c4 = (idx4 & 31) << 2;
        float4 v2 = make_float4(0.f, 0.f, 0.f, 0.f);
        if (bm + row < N_NODES) {
            float4 gv = *(const float4*)(g + (size_t)(bm + row) * 128 + c4);
            v2.x = fmaf(bnp_s[c4 + 0], gv.x, bnp_s[128 + c4 + 0]);
            v2.y = fmaf(bnp_s[c4 + 1], gv.y, bnp_s[128 + c4 + 1]);
            v2.z = fmaf(bnp_s[c4 + 2], gv.z, bnp_s[128 + c4 + 2]);
            v2.w = fmaf(bnp_s[c4 + 3], gv.w, bnp_s[128 + c4 + 3]);
        }
        unsigned short b0 = f2bf(v2.x), b1 = f2bf(v2.y), b2 = f2bf(v2.z), b3 = f2bf(v2.w);
        *(bf16x4*)(A2h + row * 136 + c4) = (bf16x4){(short)b0, (short)b1, (short)b2, (short)b3};
        *(bf16x4*)(A2l + row * 136 + c4) = (bf16x4){(short)f2bf(v2.x - bf2f(b0)), (short)f2bf(v2.y - bf2f(b1)),
                                                    (short)f2bf(v2.z - bf2f(b2)), (short)f2bf(v2.w - bf2f(b3))};
    }
    __syncthreads();

    const int w = t >> 6, lane = t & 63;
    const int wr = w >> 1, wc = w & 1;
    const int lr = lane & 15, lg = lane >> 4;
    f32x4 acc[2][2] = {};
    const size_t bofs0 = (size_t)(bn + wc * 32 + lr) * 128 + lg * 8;
#pragma unroll
    for (int kk = 0; kk < 4; kk++) {
        bf16x8 a1f[2], a2f[2], b1h[2], b2h[2];
#pragma unroll
        for (int ni = 0; ni < 2; ni++) {
            size_t o = bofs0 + (size_t)ni * 16 * 128 + kk * 32;
            b1h[ni] = *(const bf16x8*)(w1h + o);
            b2h[ni] = *(const bf16x8*)(w2h + o);
        }
        int ko = kk * 32 + lg * 8;
#pragma unroll
        for (int mi = 0; mi < 2; mi++) {
            int r = wr * 32 + mi * 16 + lr;
            a1f[mi] = *(const bf16x8*)(A1h + r * 136 + ko);
            a2f[mi] = *(const bf16x8*)(A2h + r * 136 + ko);
        }
#pragma unroll
        for (int mi = 0; mi < 2; mi++)
#pragma unroll
            for (int ni = 0; ni < 2; ni++) {
                acc[mi][ni] = __builtin_amdgcn_mfma_f32_16x16x32_bf16(a1f[mi], b1h[ni], acc[mi][ni], 0, 0, 0);
                acc[mi][ni] = __builtin_amdgcn_mfma_f32_16x16x32_bf16(a2f[mi], b2h[ni], acc[mi][ni], 0, 0, 0);
            }
    }
#pragma unroll
    for (int mi = 0; mi < 2; mi++) {
#pragma unroll
        for (int ni = 0; ni < 2; ni++) {
            int n = bn + wc * 32 + ni * 16 + lr;
            float bsum = bin[n] + bout[n];
#pragma unroll
            for (int r = 0; r < 4; r++) {
                int lrow = wr * 32 + mi * 16 + lg * 4 + r;
                float hbnv = bf2f((unsigned short)A2h[lrow * 136 + n]) + bf2f((unsigned short)A2l[lrow * 136 + n]);
                float hv   = bf2f((unsigned short)A1h[lrow * 136 + n]);
                float gt   = 1.f / (1.f + __expf(-(acc[mi][ni][r] + bsum)));
                acc[mi][ni][r] = fmaxf(gt * hbnv + (1.f - gt) * hv, 0.f);
            }
        }
    }
    __syncthreads();
#pragma unroll
    for (int mi = 0; mi < 2; mi++)
#pragma unroll
        for (int ni = 0; ni < 2; ni++) {
            int n = bn + wc * 32 + ni * 16 + lr;
#pragma unroll
            for (int r = 0; r < 4; r++) {
                int lrow = wr * 32 + mi * 16 + lg * 4 + r;
                A1h[lrow * 136 + n] = (short)f2bf(acc[mi][ni][r]);
            }
        }
    __syncthreads();
#pragma unroll
    for (int i2 = 0; i2 < 2; i2++) {
        int idx8 = t + i2 * 256;
        int row = idx8 >> 3, c8 = (idx8 & 7) << 3;
        int m = bm + row;
        if (m < N_NODES)
            *(bf16x8*)(houtb + (size_t)m * 128 + bn + c8) = *(const bf16x8*)(A1h + row * 136 + bn + c8);
    }
}

// ---------------- fused gather: single pass, 4-edge load-clustered ----------------
__global__ __launch_bounds__(256) void gat_gather(const int* __restrict__ rowptr,
                                                  const int* __restrict__ csr_src,
                                                  const float* __restrict__ al_s,
                                                  const float* __restrict__ al_d,
                                                  const unsigned short* __restrict__ hfullb,
                                                  const float* __restrict__ conv_b,
                                                  float* __restrict__ g,
                                                  float* __restrict__ bnsum,
                                                  float* __restrict__ bnsum2) {
    const int lane = threadIdx.x & 63;
    const int wib  = threadIdx.x >> 6;
    const int gwid = blockIdx.x * 4 + wib;
    const int nw   = gridDim.x * 4;
    const int h    = lane >> 4;
    const int sub  = lane & 15;
    float s1[8] = {}, s2[8] = {};

    for (int n = gwid; n < N_NODES; n += nw) {
        const int e0 = rowptr[n], e1 = rowptr[n + 1];
        const float ald_h = al_d[n * 4 + h];

        float acc[8] = {};
        float zs = 0.f;
        int i = e0;
        for (; i + 3 < e1; i += 4) {
            int sA = csr_src[i], sB = csr_src[i + 1], sC = csr_src[i + 2], sD = csr_src[i + 3];
            bf16x8 ha = *(const bf16x8*)(hfullb + (size_t)sA * 512 + lane * 8);
            bf16x8 hb = *(const bf16x8*)(hfullb + (size_t)sB * 512 + lane * 8);
            bf16x8 hc = *(const bf16x8*)(hfullb + (size_t)sC * 512 + lane * 8);
            bf16x8 hd = *(const bf16x8*)(hfullb + (size_t)sD * 512 + lane * 8);
            float vA = al_s[sA * 4 + h] + ald_h; vA = (vA > 0.f) ? vA : 0.2f * vA;
            float vB = al_s[sB * 4 + h] + ald_h; vB = (vB > 0.f) ? vB : 0.2f * vB;
            float vC = al_s[sC * 4 + h] + ald_h; vC = (vC > 0.f) ? vC : 0.2f * vC;
            float vD = al_s[sD * 4 + h] + ald_h; vD = (vD > 0.f) ? vD : 0.2f * vD;
            float exA = __expf(vA), exB = __expf(vB), exC = __expf(vC), exD = __expf(vD);
            zs += (exA + exB) + (exC + exD);
#pragma unroll
            for (int j = 0; j < 8; j++) {
                float a = fmaf(exA, bf2f((unsigned short)ha[j]), acc[j]);
                a = fmaf(exB, bf2f((unsigned short)hb[j]), a);
                a = fmaf(exC, bf2f((unsigned short)hc[j]), a);
                acc[j] = fmaf(exD, bf2f((unsigned short)hd[j]), a);
            }
        }
        for (; i < e1; i++) {
            int sA = csr_src[i];
            bf16x8 ha = *(const bf16x8*)(hfullb + (size_t)sA * 512 + lane * 8);
            float vA = al_s[sA * 4 + h] + ald_h; vA = (vA > 0.f) ? vA : 0.2f * vA;
            float exA = __expf(vA);
            zs += exA;
#pragma unroll
            for (int j = 0; j < 8; j++)
                acc[j] = fmaf(exA, bf2f((unsigned short)ha[j]), acc[j]);
        }

        float inv = 0.25f / (zs + 1e-16f);
#pragma unroll
        for (int j = 0; j < 8; j++) {
            float a = acc[j] * inv;
            a += __shfl_xor(a, 16);
            a += __shfl_xor(a, 32);
            acc[j] = a;
        }
        if (lane < 16) {
            float o[8];
#pragma unroll
            for (int j = 0; j < 8; j++) {
                float tv = acc[j] + conv_b[sub * 8 + j];
                o[j] = tv;
                s1[j] += tv;
                s2[j] = fmaf(tv, tv, s2[j]);
            }
            float* gp = g + (size_t)n * 128 + sub * 8;
            *(float4*)gp       = make_float4(o[0], o[1], o[2], o[3]);
            *(float4*)(gp + 4) = make_float4(o[4], o[5], o[6], o[7]);
        }
    }

    __shared__ float redA[4][128], redB[4][128];
    if (lane < 16) {
#pragma unroll
        for (int j = 0; j < 8; j++) {
            redA[wib][sub * 8 + j] = s1[j];
            redB[wib][sub * 8 + j] = s2[j];
        }
    }
    __syncthreads();
    int t = threadIdx.x;
    if (t < 128) {
        atomicAdd(&bnsum[t], redA[0][t] + redA[1][t] + redA[2][t] + redA[3][t]);
    } else {
        int c = t - 128;
        atomicAdd(&bnsum2[c], redB[0][c] + redB[1][c] + redB[2][c] + redB[3][c]);
    }
}

// ---------------- pooling + MLP head fused ----------------
__global__ __launch_bounds__(256) void pool_head(const short* __restrict__ hb,
                                                 const int* __restrict__ gstart,
                                                 const float* __restrict__ fc1W,
                                                 const float* __restrict__ fc1b,
                                                 const float* __restrict__ fc3W,
                                                 const float* __restrict__ fc3b,
                                                 float* __restrict__ out) {
    int gid = blockIdx.x, t = threadIdx.x;
    int lo = gstart[gid], hi = gstart[gid + 1];
    int c = t & 127, half = t >> 7;
    float s = 0.f;
    for (int n = lo + half; n < hi; n += 2)
        s += bf2f((unsigned short)hb[(size_t)n * 128 + c]);
    __shared__ float sh[256];
    __shared__ float hg[128], a1[128];
    sh[t] = s;
    __syncthreads();
    if (half == 0) {
        float cc = fmaxf((float)(hi - lo), 1.f);
        hg[c] = (sh[c] + sh[c + 128]) / cc;
    }
    __syncthreads();
    if (t < 128) {
        float v = fc1b[t];
        for (int c2 = 0; c2 < 128; c2++) v = fmaf(hg[c2], fc1W[c2 * 128 + t], v);
        a1[t] = fmaxf(v, 0.f);
    }
    __syncthreads();
    if (t < 16) {
        float o = fc3b[t];
        for (int j = 0; j < 128; j++) o = fmaf(a1[j], fc3W[j * 16 + t], o);
        out[gid * 16 + t] = o;
    }
}

extern "C" void kernel_launch(void* const* d_in, const int* in_sizes, int n_in,
                              void* d_out, int out_size, void* d_ws, size_t ws_size,
                              hipStream_t stream) {
    const float* x       = (const float*)d_in[0];
    const int*   ei      = (const int*)d_in[1];
    const int*   batch   = (const int*)d_in[2];
    const float* W       = (const float*)d_in[3];
    const float* att_src = (const float*)d_in[4];
    const float* att_dst = (const float*)d_in[5];
    const float* conv_b  = (const float*)d_in[6];
    const float* gamma   = (const float*)d_in[7];
    const float* beta    = (const float*)d_in[8];
    const float* sk_Win  = (const float*)d_in[9];
    const float* sk_bin  = (const float*)d_in[10];
    const float* sk_Wout = (const float*)d_in[11];
    const float* sk_bout = (const float*)d_in[12];
    const float* fc1_W   = (const float*)d_in[13];
    const float* fc1_b   = (const float*)d_in[14];
    const float* fc3_W   = (const float*)d_in[15];
    const float* fc3_b   = (const float*)d_in[16];
    float* out = (float*)d_out;
    const int* ei0 = ei;
    const int* ei1 = ei + N_EDGES;

    float* ws = (float*)d_ws;
    size_t o = 0;
    unsigned short* hfullb = (unsigned short*)(ws + o); o += (size_t)N_NODES * 256;  // bf16 [N,512]
    float* gbuf   = ws + o; o += (size_t)N_NODES * 128;
    short* hbA    = (short*)(ws + o); o += (size_t)N_NODES * 64;   // bf16 [N,128] ping
    short* hbB    = (short*)(ws + o); o += (size_t)N_NODES * 64;   // pong
    float* als    = ws + o; o += N_NODES * 4;
    float* ald    = ws + o; o += N_NODES * 4;
    float* bnsum  = ws + o; o += 768;      // 3 layers x (128 sum + 128 sumsq)
    short* wt_hi   = (short*)(ws + o); o += 98304;   // 3*512*128 shorts
    short* wint_hi = (short*)(ws + o); o += 24576;   // 3*128*128 shorts
    short* woutt_hi = (short*)(ws + o); o += 24576;
    int* gstart   = (int*)(ws + o); o += 132;
    int* deg      = (int*)(ws + o); o += N_NODES;
    int* rowptr   = (int*)(ws + o); o += N_NODES + 4;
    int* wofs     = (int*)(ws + o); o += N_NODES;
    int* scantmp  = (int*)(ws + o); o += N_NODES;
    int* blksum   = (int*)(ws + o); o += NBLK + 2;
    int* blkoff   = (int*)(ws + o); o += NBLK + 2;
    int* csr_src  = (int*)(ws + o); o += ETOT;

    {
        void* cargs[] = {(void*)&W, (void*)&sk_Win, (void*)&sk_Wout, (void*)&x, (void*)&batch,
                         (void*)&ei0, (void*)&ei1,
                         (void*)&wt_hi, (void*)&wint_hi, (void*)&woutt_hi,
                         (void*)&hbA, (void*)&gstart,
                         (void*)&deg, (void*)&rowptr, (void*)&wofs,
                         (void*)&scantmp, (void*)&blksum, (void*)&blkoff,
                         (void*)&csr_src, (void*)&bnsum};
        hipLaunchCooperativeKernel((void*)coop_prep, dim3(1024), dim3(256), cargs, 0, stream);
    }

    // layer 0 conv
    gemm_conv<<<dim3(469, 4), 256, 0, stream>>>(hbA, wt_hi, att_src, att_dst, hfullb, als, ald);
    gat_gather<<<1024, 256, 0, stream>>>(rowptr, csr_src, als, ald, hfullb,
                                         conv_b, gbuf, bnsum, bnsum + 128);
    // fused skip(0) + conv(1)
    skip_conv<<<469, 256, 0, stream>>>(hbA, gbuf, bnsum, gamma, beta,
                                       wint_hi, woutt_hi, sk_bin, sk_bout,
                                       wt_hi + 65536, att_src + 512, att_dst + 512,
                                       hbB, hfullb, als, ald);
    gat_gather<<<1024, 256, 0, stream>>>(rowptr, csr_src, als, ald, hfullb,
                                         conv_b + 128, gbuf, bnsum + 256, bnsum + 384);
    // fused skip(1) + conv(2)
    skip_conv<<<469, 256, 0, stream>>>(hbB, gbuf, bnsum + 256, gamma + 128, beta + 128,
                                       wint_hi + 16384, woutt_hi + 16384, sk_bin + 128, sk_bout + 128,
                                       wt_hi + 131072, att_src + 1024, att_dst + 1024,
                                       hbA, hfullb, als, ald);
    gat_gather<<<1024, 256, 0, stream>>>(rowptr, csr_src, als, ald, hfullb,
                                         conv_b + 256, gbuf, bnsum + 512, bnsum + 640);
    // last skip
    skip_gate<<<dim3(469, 2), 256, 0, stream>>>(hbA, gbuf, bnsum + 512, gamma + 256, beta + 256,
                                                wint_hi + 32768, woutt_hi + 32768,
                                                sk_bin + 256, sk_bout + 256, hbB);

    pool_head<<<NGRAPH, 256, 0, stream>>>(hbB, gstart, fc1_W, fc1_b, fc3_W, fc3_b, out);
}

// Round 13
// 413.340 us; speedup vs baseline: 2.2483x; 2.2483x over previous
//
#include <hip/hip_runtime.h>
#include <hip/hip_bf16.h>

#define N_NODES 30000
#define N_EDGES 240000
#define ETOT    (N_EDGES + N_NODES)   // 270000 (self loops appended)
#define NGRAPH  128
#define NBLK    118                   // ceil(30000/256)

typedef __attribute__((ext_vector_type(8))) short bf16x8;
typedef __attribute__((ext_vector_type(4))) short bf16x4;
typedef __attribute__((ext_vector_type(4))) float f32x4;

__device__ __forceinline__ unsigned short f2bf(float f) {
    unsigned u = __float_as_uint(f);
    u += 0x7fff + ((u >> 16) & 1);        // round-to-nearest-even
    return (unsigned short)(u >> 16);
}
__device__ __forceinline__ float bf2f(unsigned short h) {
    return __uint_as_float(((unsigned)h) << 16);
}

// ---------- merged prep: weight transpose->bf16, x->bf16, graph bounds ----------
__global__ __launch_bounds__(256) void prep_kernel(const float* __restrict__ W,
                                                   const float* __restrict__ Win,
                                                   const float* __restrict__ Wout,
                                                   const float* __restrict__ x,
                                                   const int* __restrict__ batch,
                                                   short* __restrict__ wt_hi,
                                                   short* __restrict__ wint_hi,
                                                   short* __restrict__ woutt_hi,
                                                   short* __restrict__ xb,
                                                   int* __restrict__ gstart) {
    int i = blockIdx.x * 256 + threadIdx.x;
    if (i < 196608) {                       // 3*512*128
        int l = i >> 16, r = i & 65535;
        int n = r >> 7, k = r & 127;
        wt_hi[i] = (short)f2bf(W[(size_t)l * 65536 + k * 512 + n]);
    } else if (i < 245760) {                // + 3*128*128
        int j = i - 196608;
        int l = j >> 14, r = j & 16383;
        int n = r >> 7, k = r & 127;
        wint_hi[j] = (short)f2bf(Win[(size_t)l * 16384 + k * 128 + n]);
    } else if (i < 294912) {
        int j = i - 245760;
        int l = j >> 14, r = j & 16383;
        int n = r >> 7, k = r & 127;
        woutt_hi[j] = (short)f2bf(Wout[(size_t)l * 16384 + k * 128 + n]);
    } else if (i < 294912 + 480000) {       // x -> bf16, 8 floats per thread
        int j = i - 294912;
        const float4* p = (const float4*)x + (size_t)j * 2;
        float4 v0 = p[0], v1 = p[1];
        bf16x8 hv;
        hv[0] = (short)f2bf(v0.x); hv[1] = (short)f2bf(v0.y);
        hv[2] = (short)f2bf(v0.z); hv[3] = (short)f2bf(v0.w);
        hv[4] = (short)f2bf(v1.x); hv[5] = (short)f2bf(v1.y);
        hv[6] = (short)f2bf(v1.z); hv[7] = (short)f2bf(v1.w);
        *(bf16x8*)(xb + (size_t)j * 8) = hv;
    } else if (i < 294912 + 480000 + 129) { // graph segment bounds
        int t = i - 294912 - 480000;
        int lo = 0, hi = N_NODES;
        while (lo < hi) { int mid = (lo + hi) >> 1; if (batch[mid] < t) lo = mid + 1; else hi = mid; }
        gstart[t] = lo;
    }
}

// ---------- conv GEMM (bf16 x bf16) + logits + coalesced store (layer 0 only) ----
__global__ __launch_bounds__(256) void gemm_conv(const short* __restrict__ Ab,
                                                 const short* __restrict__ Bth,
                                                 const float* __restrict__ att_s,
                                                 const float* __restrict__ att_d,
                                                 unsigned short* __restrict__ hfullb,
                                                 float* __restrict__ als,
                                                 float* __restrict__ ald) {
    __shared__ short As_h[64 * 136];
    __shared__ float red_s[2][64], red_d[2][64];
    const int bm = blockIdx.x * 64;
    const int hd = blockIdx.y;
    const int bn = hd * 128;
    const int t  = threadIdx.x;
#pragma unroll
    for (int i = 0; i < 4; i++) {
        int idx8 = t + i * 256;
        int row = idx8 >> 4, c8 = (idx8 & 15) << 3;
        bf16x8 vh = {};
        if (bm + row < N_NODES)
            vh = *(const bf16x8*)(Ab + (size_t)(bm + row) * 128 + c8);
        *(bf16x8*)(As_h + row * 136 + c8) = vh;
    }
    __syncthreads();

    const int w = t >> 6, lane = t & 63;
    const int wr = w >> 1, wc = w & 1;
    const int lr = lane & 15, lg = lane >> 4;
    f32x4 acc[2][4] = {};
    const size_t bofs0 = (size_t)(bn + wc * 64 + lr) * 128 + lg * 8;
#pragma unroll
    for (int kk = 0; kk < 4; kk++) {
        bf16x8 ah[2], bh[4];
#pragma unroll
        for (int ni = 0; ni < 4; ni++) {
            size_t o = bofs0 + (size_t)ni * 16 * 128 + kk * 32;
            bh[ni] = *(const bf16x8*)(Bth + o);
        }
        int ko = kk * 32 + lg * 8;
#pragma unroll
        for (int mi = 0; mi < 2; mi++) {
            int r = wr * 32 + mi * 16 + lr;
            ah[mi] = *(const bf16x8*)(As_h + r * 136 + ko);
        }
#pragma unroll
        for (int mi = 0; mi < 2; mi++)
#pragma unroll
            for (int ni = 0; ni < 4; ni++)
                acc[mi][ni] = __builtin_amdgcn_mfma_f32_16x16x32_bf16(ah[mi], bh[ni], acc[mi][ni], 0, 0, 0);
    }
    float as_c[4], ad_c[4];
#pragma unroll
    for (int ni = 0; ni < 4; ni++) {
        int cc = wc * 64 + ni * 16 + lr;
        as_c[ni] = att_s[hd * 128 + cc];
        ad_c[ni] = att_d[hd * 128 + cc];
    }
#pragma unroll
    for (int mi = 0; mi < 2; mi++) {
#pragma unroll
        for (int r = 0; r < 4; r++) {
            float ps = 0.f, pd = 0.f;
#pragma unroll
            for (int ni = 0; ni < 4; ni++) {
                ps = fmaf(acc[mi][ni][r], as_c[ni], ps);
                pd = fmaf(acc[mi][ni][r], ad_c[ni], pd);
            }
#pragma unroll
            for (int off = 1; off < 16; off <<= 1) {
                ps += __shfl_xor(ps, off);
                pd += __shfl_xor(pd, off);
            }
            if (lr == 0) {
                int row = wr * 32 + mi * 16 + lg * 4 + r;
                red_s[wc][row] = ps;
                red_d[wc][row] = pd;
            }
        }
    }
    __syncthreads();
#pragma unroll
    for (int mi = 0; mi < 2; mi++)
#pragma unroll
        for (int ni = 0; ni < 4; ni++) {
            int nl = wc * 64 + ni * 16 + lr;
#pragma unroll
            for (int r = 0; r < 4; r++) {
                int row = wr * 32 + mi * 16 + lg * 4 + r;
                As_h[row * 136 + nl] = (short)f2bf(acc[mi][ni][r]);
            }
        }
    if (t < 64) {
        int m = bm + t;
        if (m < N_NODES) als[m * 4 + hd] = red_s[0][t] + red_s[1][t];
    } else if (t < 128) {
        int tt = t - 64;
        int m = bm + tt;
        if (m < N_NODES) ald[m * 4 + hd] = red_d[0][tt] + red_d[1][tt];
    }
    __syncthreads();
#pragma unroll
    for (int i2 = 0; i2 < 4; i2++) {
        int idx8 = t + i2 * 256;
        int row = idx8 >> 4, c8 = (idx8 & 15) << 3;
        int m = bm + row;
        if (m < N_NODES)
            *(bf16x8*)(hfullb + (size_t)m * 512 + bn + c8) = *(const bf16x8*)(As_h + row * 136 + c8);
    }
}

// ---------- fused skip(l) + conv(l+1): one 64-row block does both ----------
__global__ __launch_bounds__(256) void skip_conv(const short* __restrict__ hinb,
                                                 const float* __restrict__ g,
                                                 const float* __restrict__ bnsum,
                                                 const float* __restrict__ gamma,
                                                 const float* __restrict__ beta,
                                                 const short* __restrict__ w1h,
                                                 const short* __restrict__ w2h,
                                                 const float* __restrict__ bin,
                                                 const float* __restrict__ bout,
                                                 const short* __restrict__ wtn,    // conv W^T (l+1) [512][128]
                                                 const float* __restrict__ att_s,  // (l+1)
                                                 const float* __restrict__ att_d,
                                                 short* __restrict__ houtb,
                                                 unsigned short* __restrict__ hfullb,
                                                 float* __restrict__ als,
                                                 float* __restrict__ ald) {
    __shared__ short A1h[64 * 136], A2h[64 * 136];
    __shared__ float bnp_s[256];
    __shared__ float redS[4][64], redD[4][64];
    const int bm = blockIdx.x * 64;
    const int t  = threadIdx.x;
    if (t < 128) {
        float inv = 1.f / (float)N_NODES;
        float mu  = bnsum[t] * inv;
        float var = bnsum[128 + t] * inv - mu * mu;
        float rs  = rsqrtf(var + 1e-5f);
        float sc  = gamma[t] * rs;
        bnp_s[t]       = sc;
        bnp_s[128 + t] = beta[t] - mu * sc;
    }
    __syncthreads();
    // A1: bf16 hin tile; A2: bn(g) rounded to bf16 (MFMA operand only)
#pragma unroll
    for (int i = 0; i < 4; i++) {
        int idx8 = t + i * 256;
        int row = idx8 >> 4, c8 = (idx8 & 15) << 3;
        bf16x8 vh = {};
        if (bm + row < N_NODES)
            vh = *(const bf16x8*)(hinb + (size_t)(bm + row) * 128 + c8);
        *(bf16x8*)(A1h + row * 136 + c8) = vh;
    }
#pragma unroll
    for (int i = 0; i < 8; i++) {
        int idx4 = t + i * 256;
        int row = idx4 >> 5, c4 = (idx4 & 31) << 2;
        float4 v2 = make_float4(0.f, 0.f, 0.f, 0.f);
        if (bm + row < N_NODES) {
            float4 gv = *(const float4*)(g + (size_t)(bm + row) * 128 + c4);
            v2.x = fmaf(bnp_s[c4 + 0], gv.x, bnp_s[128 + c4 + 0]);
            v2.y = fmaf(bnp_s[c4 + 1], gv.y, bnp_s[128 + c4 + 1]);
            v2.z = fmaf(bnp_s[c4 + 2], gv.z, bnp_s[128 + c4 + 2]);
            v2.w = fmaf(bnp_s[c4 + 3], gv.w, bnp_s[128 + c4 + 3]);
        }
        *(bf16x4*)(A2h + row * 136 + c4) = (bf16x4){(short)f2bf(v2.x), (short)f2bf(v2.y),
                                                    (short)f2bf(v2.z), (short)f2bf(v2.w)};
    }
    __syncthreads();

    const int w = t >> 6, lane = t & 63;
    const int wr = w >> 1, wc = w & 1;
    const int lr = lane & 15, lg = lane >> 4;

    // phase A: P = hin@W1 + bn(g)@W2 over full 64x128; gate+relu
    {
        f32x4 acc[2][4] = {};
        const size_t bo = (size_t)(wc * 64 + lr) * 128 + lg * 8;
#pragma unroll
        for (int kk = 0; kk < 4; kk++) {
            bf16x8 a1[2], a2[2], b1[4], b2[4];
#pragma unroll
            for (int ni = 0; ni < 4; ni++) {
                size_t o = bo + (size_t)ni * 2048 + kk * 32;
                b1[ni] = *(const bf16x8*)(w1h + o);
                b2[ni] = *(const bf16x8*)(w2h + o);
            }
            int ko = kk * 32 + lg * 8;
#pragma unroll
            for (int mi = 0; mi < 2; mi++) {
                int r = wr * 32 + mi * 16 + lr;
                a1[mi] = *(const bf16x8*)(A1h + r * 136 + ko);
                a2[mi] = *(const bf16x8*)(A2h + r * 136 + ko);
            }
#pragma unroll
            for (int mi = 0; mi < 2; mi++)
#pragma unroll
                for (int ni = 0; ni < 4; ni++) {
                    acc[mi][ni] = __builtin_amdgcn_mfma_f32_16x16x32_bf16(a1[mi], b1[ni], acc[mi][ni], 0, 0, 0);
                    acc[mi][ni] = __builtin_amdgcn_mfma_f32_16x16x32_bf16(a2[mi], b2[ni], acc[mi][ni], 0, 0, 0);
                }
        }
        // gate + relu (hbn from fp32 g; hv from bf16 state = exact)
#pragma unroll
        for (int mi = 0; mi < 2; mi++)
#pragma unroll
            for (int ni = 0; ni < 4; ni++) {
                int n = wc * 64 + ni * 16 + lr;
                float bsum = bin[n] + bout[n];
                float sc = bnp_s[n], shb = bnp_s[128 + n];
#pragma unroll
                for (int r = 0; r < 4; r++) {
                    int lrow = wr * 32 + mi * 16 + lg * 4 + r;
                    int m = bm + lrow;
                    float gv = (m < N_NODES) ? g[(size_t)m * 128 + n] : 0.f;
                    float hbnv = fmaf(sc, gv, shb);
                    float hv   = bf2f((unsigned short)A1h[lrow * 136 + n]);
                    float gt   = 1.f / (1.f + __expf(-(acc[mi][ni][r] + bsum)));
                    acc[mi][ni][r] = fmaxf(gt * hbnv + (1.f - gt) * hv, 0.f);
                }
            }
        __syncthreads();          // A tiles dead
        // stage hout (bf16) into A1h
#pragma unroll
        for (int mi = 0; mi < 2; mi++)
#pragma unroll
            for (int ni = 0; ni < 4; ni++) {
                int n = wc * 64 + ni * 16 + lr;
#pragma unroll
                for (int r = 0; r < 4; r++) {
                    int lrow = wr * 32 + mi * 16 + lg * 4 + r;
                    A1h[lrow * 136 + n] = (short)f2bf(acc[mi][ni][r]);
                }
            }
        __syncthreads();
        // coalesced houtb store (64x128)
#pragma unroll
        for (int i2 = 0; i2 < 4; i2++) {
            int idx8 = t + i2 * 256;
            int row = idx8 >> 4, c8 = (idx8 & 15) << 3;
            int m = bm + row;
            if (m < N_NODES)
                *(bf16x8*)(houtb + (size_t)m * 128 + c8) = *(const bf16x8*)(A1h + row * 136 + c8);
        }
    }

    // phase B: conv(l+1) on hout tile in A1h; wave = head
    f32x4 c2[4][8] = {};
    const int hd = w;
    const size_t bo2 = (size_t)(hd * 128 + lr) * 128 + lg * 8;
#pragma unroll
    for (int kk = 0; kk < 4; kk++) {
        bf16x8 ah2[4], bh2[8];
#pragma unroll
        for (int ni = 0; ni < 8; ni++)
            bh2[ni] = *(const bf16x8*)(wtn + bo2 + (size_t)ni * 2048 + kk * 32);
        int ko = kk * 32 + lg * 8;
#pragma unroll
        for (int mi = 0; mi < 4; mi++)
            ah2[mi] = *(const bf16x8*)(A1h + (mi * 16 + lr) * 136 + ko);
#pragma unroll
        for (int mi = 0; mi < 4; mi++)
#pragma unroll
            for (int ni = 0; ni < 8; ni++)
                c2[mi][ni] = __builtin_amdgcn_mfma_f32_16x16x32_bf16(ah2[mi], bh2[ni], c2[mi][ni], 0, 0, 0);
    }
    // logits for head hd (full 128-col sum within wave)
    {
        float asc[8], adc[8];
#pragma unroll
        for (int ni = 0; ni < 8; ni++) {
            int cc = ni * 16 + lr;
            asc[ni] = att_s[hd * 128 + cc];
            adc[ni] = att_d[hd * 128 + cc];
        }
#pragma unroll
        for (int mi = 0; mi < 4; mi++)
#pragma unroll
            for (int r = 0; r < 4; r++) {
                float ps = 0.f, pd = 0.f;
#pragma unroll
                for (int ni = 0; ni < 8; ni++) {
                    ps = fmaf(c2[mi][ni][r], asc[ni], ps);
                    pd = fmaf(c2[mi][ni][r], adc[ni], pd);
                }
#pragma unroll
                for (int off = 1; off < 16; off <<= 1) {
                    ps += __shfl_xor(ps, off);
                    pd += __shfl_xor(pd, off);
                }
                if (lr == 0) {
                    int row = mi * 16 + lg * 4 + r;
                    redS[hd][row] = ps;
                    redD[hd][row] = pd;
                }
            }
    }
    __syncthreads();              // MFMAs + red writes done; A1h/A2h free
    // round 0: waves 0,1 stage heads 0,1
    if (w < 2) {
        short* dst = (w == 0) ? A1h : A2h;
#pragma unroll
        for (int mi = 0; mi < 4; mi++)
#pragma unroll
            for (int ni = 0; ni < 8; ni++)
#pragma unroll
                for (int r = 0; r < 4; r++)
                    dst[(mi * 16 + lg * 4 + r) * 136 + ni * 16 + lr] = (short)f2bf(c2[mi][ni][r]);
    }
    // als/ald (4 heads x 64 rows; redS/redD synced above)
    {
        int hd2 = t >> 6, row = t & 63;
        int m = bm + row;
        if (m < N_NODES) {
            als[m * 4 + hd2] = redS[hd2][row];
            ald[m * 4 + hd2] = redD[hd2][row];
        }
    }
    __syncthreads();
    // store heads 0,1 (cols 0..255)
#pragma unroll
    for (int it = 0; it < 8; it++) {
        int idx = t + it * 256;
        int row = idx >> 5, c8 = (idx & 31) << 3;
        int m = bm + row;
        if (m < N_NODES) {
            const short* src = (c8 < 128) ? A1h : A2h;
            *(bf16x8*)(hfullb + (size_t)m * 512 + c8) = *(const bf16x8*)(src + row * 136 + (c8 & 127));
        }
    }
    __syncthreads();
    // round 1: waves 2,3 stage heads 2,3
    if (w >= 2) {
        short* dst = (w == 2) ? A1h : A2h;
#pragma unroll
        for (int mi = 0; mi < 4; mi++)
#pragma unroll
            for (int ni = 0; ni < 8; ni++)
#pragma unroll
                for (int r = 0; r < 4; r++)
                    dst[(mi * 16 + lg * 4 + r) * 136 + ni * 16 + lr] = (short)f2bf(c2[mi][ni][r]);
    }
    __syncthreads();
#pragma unroll
    for (int it = 0; it < 8; it++) {
        int idx = t + it * 256;
        int row = idx >> 5, c8 = (idx & 31) << 3;
        int m = bm + row;
        if (m < N_NODES) {
            const short* src = (c8 < 128) ? A1h : A2h;
            *(bf16x8*)(hfullb + (size_t)m * 512 + 256 + c8) = *(const bf16x8*)(src + row * 136 + (c8 & 127));
        }
    }
}

// ---------- plain skip (last layer) ----------
__global__ __launch_bounds__(256) void skip_gate(const short* __restrict__ hinb,
                                                 const float* __restrict__ g,
                                                 const float* __restrict__ bnsum,
                                                 const float* __restrict__ gamma,
                                                 const float* __restrict__ beta,
                                                 const short* __restrict__ w1h,
                                                 const short* __restrict__ w2h,
                                                 const float* __restrict__ bin, const float* __restrict__ bout,
                                                 short* __restrict__ houtb) {
    __shared__ short A1h[64 * 136], A2h[64 * 136], A2l[64 * 136];
    __shared__ float bnp_s[256];
    const int bm = blockIdx.x * 64;
    const int bn = blockIdx.y * 64;
    const int t  = threadIdx.x;
    if (t < 128) {
        float inv = 1.f / (float)N_NODES;
        float mu  = bnsum[t] * inv;
        float var = bnsum[128 + t] * inv - mu * mu;
        float rs  = rsqrtf(var + 1e-5f);
        float sc  = gamma[t] * rs;
        bnp_s[t]       = sc;
        bnp_s[128 + t] = beta[t] - mu * sc;
    }
    __syncthreads();
#pragma unroll
    for (int i = 0; i < 4; i++) {
        int idx8 = t + i * 256;
        int row = idx8 >> 4, c8 = (idx8 & 15) << 3;
        bf16x8 vh = {};
        if (bm + row < N_NODES)
            vh = *(const bf16x8*)(hinb + (size_t)(bm + row) * 128 + c8);
        *(bf16x8*)(A1h + row * 136 + c8) = vh;
    }
#pragma unroll
    for (int i = 0; i < 8; i++) {
        int idx4 = t + i * 256;
        int row = idx4 >> 5, c4 = (idx4 & 31) << 2;
        float4 v2 = make_float4(0.f, 0.f, 0.f, 0.f);
        if (bm + row < N_NODES) {
            float4 gv = *(const float4*)(g + (size_t)(bm + row) * 128 + c4);
            v2.x = fmaf(bnp_s[c4 + 0], gv.x, bnp_s[128 + c4 + 0]);
            v2.y = fmaf(bnp_s[c4 + 1], gv.y, bnp_s[128 + c4 + 1]);
            v2.z = fmaf(bnp_s[c4 + 2], gv.z, bnp_s[128 + c4 + 2]);
            v2.w = fmaf(bnp_s[c4 + 3], gv.w, bnp_s[128 + c4 + 3]);
        }
        unsigned short b0 = f2bf(v2.x), b1 = f2bf(v2.y), b2 = f2bf(v2.z), b3 = f2bf(v2.w);
        *(bf16x4*)(A2h + row * 136 + c4) = (bf16x4){(short)b0, (short)b1, (short)b2, (short)b3};
        *(bf16x4*)(A2l + row * 136 + c4) = (bf16x4){(short)f2bf(v2.x - bf2f(b0)), (short)f2bf(v2.y - bf2f(b1)),
                                                    (short)f2bf(v2.z - bf2f(b2)), (short)f2bf(v2.w - bf2f(b3))};
    }
    __syncthreads();

    const int w = t >> 6, lane = t & 63;
    const int wr = w >> 1, wc = w & 1;
    const int lr = lane & 15, lg = lane >> 4;
    f32x4 acc[2][2] = {};
    const size_t bofs0 = (size_t)(bn + wc * 32 + lr) * 128 + lg * 8;
#pragma unroll
    for (int kk = 0; kk < 4; kk++) {
        bf16x8 a1f[2], a2f[2], b1h[2], b2h[2];
#pragma unroll
        for (int ni = 0; ni < 2; ni++) {
            size_t o = bofs0 + (size_t)ni * 16 * 128 + kk * 32;
            b1h[ni] = *(const bf16x8*)(w1h + o);
            b2h[ni] = *(const bf16x8*)(w2h + o);
        }
        int ko = kk * 32 + lg * 8;
#pragma unroll
        for (int mi = 0; mi < 2; mi++) {
            int r = wr * 32 + mi * 16 + lr;
            a1f[mi] = *(const bf16x8*)(A1h + r * 136 + ko);
            a2f[mi] = *(const bf16x8*)(A2h + r * 136 + ko);
        }
#pragma unroll
        for (int mi = 0; mi < 2; mi++)
#pragma unroll
            for (int ni = 0; ni < 2; ni++) {
                acc[mi][ni] = __builtin_amdgcn_mfma_f32_16x16x32_bf16(a1f[mi], b1h[ni], acc[mi][ni], 0, 0, 0);
                acc[mi][ni] = __builtin_amdgcn_mfma_f32_16x16x32_bf16(a2f[mi], b2h[ni], acc[mi][ni], 0, 0, 0);
            }
    }
#pragma unroll
    for (int mi = 0; mi < 2; mi++) {
#pragma unroll
        for (int ni = 0; ni < 2; ni++) {
            int n = bn + wc * 32 + ni * 16 + lr;
            float bsum = bin[n] + bout[n];
#pragma unroll
            for (int r = 0; r < 4; r++) {
                int lrow = wr * 32 + mi * 16 + lg * 4 + r;
                float hbnv = bf2f((unsigned short)A2h[lrow * 136 + n]) + bf2f((unsigned short)A2l[lrow * 136 + n]);
                float hv   = bf2f((unsigned short)A1h[lrow * 136 + n]);
                float gt   = 1.f / (1.f + __expf(-(acc[mi][ni][r] + bsum)));
                acc[mi][ni][r] = fmaxf(gt * hbnv + (1.f - gt) * hv, 0.f);
            }
        }
    }
    __syncthreads();
#pragma unroll
    for (int mi = 0; mi < 2; mi++)
#pragma unroll
        for (int ni = 0; ni < 2; ni++) {
            int n = bn + wc * 32 + ni * 16 + lr;
#pragma unroll
            for (int r = 0; r < 4; r++) {
                int lrow = wr * 32 + mi * 16 + lg * 4 + r;
                A1h[lrow * 136 + n] = (short)f2bf(acc[mi][ni][r]);
            }
        }
    __syncthreads();
#pragma unroll
    for (int i2 = 0; i2 < 2; i2++) {
        int idx8 = t + i2 * 256;
        int row = idx8 >> 3, c8 = (idx8 & 7) << 3;
        int m = bm + row;
        if (m < N_NODES)
            *(bf16x8*)(houtb + (size_t)m * 128 + bn + c8) = *(const bf16x8*)(A1h + row * 136 + bn + c8);
    }
}

// ---------------- CSR build ----------------
__global__ __launch_bounds__(256) void deg_kernel(const int* __restrict__ ei1,
                                                  int* __restrict__ deg) {
    int e = blockIdx.x * 256 + threadIdx.x;
    if (e >= ETOT) return;
    int d = (e < N_EDGES) ? ei1[e] : (e - N_EDGES);
    atomicAdd(&deg[d], 1);
}

__global__ __launch_bounds__(256) void scan1(const int* __restrict__ deg,
                                             int* __restrict__ tmp,
                                             int* __restrict__ blksum) {
    int i = blockIdx.x * 256 + threadIdx.x;
    int v = (i < N_NODES) ? deg[i] : 0;
    __shared__ int sh[256];
    sh[threadIdx.x] = v;
    __syncthreads();
    int acc = v;
    for (int off = 1; off < 256; off <<= 1) {
        int u = (threadIdx.x >= off) ? sh[threadIdx.x - off] : 0;
        __syncthreads();
        acc += u;
        sh[threadIdx.x] = acc;
        __syncthreads();
    }
    if (i < N_NODES) tmp[i] = acc - v;     // exclusive within block
    if (threadIdx.x == 255) blksum[blockIdx.x] = acc;
}

__global__ void scan2(const int* __restrict__ blksum, int* __restrict__ blkoff) {
    int t = threadIdx.x;                   // 128 threads >= NBLK
    int v = (t < NBLK) ? blksum[t] : 0;
    __shared__ int sh[128];
    sh[t] = v;
    __syncthreads();
    int acc = v;
    for (int off = 1; off < 128; off <<= 1) {
        int u = (t >= off) ? sh[t - off] : 0;
        __syncthreads();
        acc += u;
        sh[t] = acc;
        __syncthreads();
    }
    if (t < NBLK) blkoff[t] = acc - v;     // exclusive block offset
}

__global__ __launch_bounds__(256) void scan3(const int* __restrict__ tmp,
                                             const int* __restrict__ blkoff,
                                             int* __restrict__ rowptr,
                                             int* __restrict__ wofs) {
    int i = blockIdx.x * 256 + threadIdx.x;
    if (i == 0) rowptr[N_NODES] = ETOT;
    if (i < N_NODES) {
        int r = tmp[i] + blkoff[blockIdx.x];
        rowptr[i] = r;
        wofs[i]   = r;
    }
}

__global__ __launch_bounds__(256) void scatter_kernel(const int* __restrict__ ei0,
                                                      const int* __restrict__ ei1,
                                                      int* __restrict__ wofs,
                                                      int* __restrict__ csr_src) {
    int e = blockIdx.x * 256 + threadIdx.x;
    if (e >= ETOT) return;
    int s = (e < N_EDGES) ? ei0[e] : (e - N_EDGES);
    int d = (e < N_EDGES) ? ei1[e] : (e - N_EDGES);
    int pos = atomicAdd(&wofs[d], 1);
    csr_src[pos] = s;
}

// ---------------- fused gather: single pass, 4-edge load-clustered ----------------
__global__ __launch_bounds__(256) void gat_gather(const int* __restrict__ rowptr,
                                                  const int* __restrict__ csr_src,
                                                  const float* __restrict__ al_s,
                                                  const float* __restrict__ al_d,
                                                  const unsigned short* __restrict__ hfullb,
                                                  const float* __restrict__ conv_b,
                                                  float* __restrict__ g,
                                                  float* __restrict__ bnsum,
                                                  float* __restrict__ bnsum2) {
    const int lane = threadIdx.x & 63;
    const int wib  = threadIdx.x >> 6;
    const int gwid = blockIdx.x * 4 + wib;
    const int nw   = gridDim.x * 4;
    const int h    = lane >> 4;
    const int sub  = lane & 15;
    float s1[8] = {}, s2[8] = {};

    for (int n = gwid; n < N_NODES; n += nw) {
        const int e0 = rowptr[n], e1 = rowptr[n + 1];
        const float ald_h = al_d[n * 4 + h];

        float acc[8] = {};
        float zs = 0.f;
        int i = e0;
        for (; i + 3 < e1; i += 4) {
            int sA = csr_src[i], sB = csr_src[i + 1], sC = csr_src[i + 2], sD = csr_src[i + 3];
            bf16x8 ha = *(const bf16x8*)(hfullb + (size_t)sA * 512 + lane * 8);
            bf16x8 hb = *(const bf16x8*)(hfullb + (size_t)sB * 512 + lane * 8);
            bf16x8 hc = *(const bf16x8*)(hfullb + (size_t)sC * 512 + lane * 8);
            bf16x8 hd = *(const bf16x8*)(hfullb + (size_t)sD * 512 + lane * 8);
            float vA = al_s[sA * 4 + h] + ald_h; vA = (vA > 0.f) ? vA : 0.2f * vA;
            float vB = al_s[sB * 4 + h] + ald_h; vB = (vB > 0.f) ? vB : 0.2f * vB;
            float vC = al_s[sC * 4 + h] + ald_h; vC = (vC > 0.f) ? vC : 0.2f * vC;
            float vD = al_s[sD * 4 + h] + ald_h; vD = (vD > 0.f) ? vD : 0.2f * vD;
            float exA = __expf(vA), exB = __expf(vB), exC = __expf(vC), exD = __expf(vD);
            zs += (exA + exB) + (exC + exD);
#pragma unroll
            for (int j = 0; j < 8; j++) {
                float a = fmaf(exA, bf2f((unsigned short)ha[j]), acc[j]);
                a = fmaf(exB, bf2f((unsigned short)hb[j]), a);
                a = fmaf(exC, bf2f((unsigned short)hc[j]), a);
                acc[j] = fmaf(exD, bf2f((unsigned short)hd[j]), a);
            }
        }
        for (; i < e1; i++) {
            int sA = csr_src[i];
            bf16x8 ha = *(const bf16x8*)(hfullb + (size_t)sA * 512 + lane * 8);
            float vA = al_s[sA * 4 + h] + ald_h; vA = (vA > 0.f) ? vA : 0.2f * vA;
            float exA = __expf(vA);
            zs += exA;
#pragma unroll
            for (int j = 0; j < 8; j++)
                acc[j] = fmaf(exA, bf2f((unsigned short)ha[j]), acc[j]);
        }

        float inv = 0.25f / (zs + 1e-16f);
#pragma unroll
        for (int j = 0; j < 8; j++) {
            float a = acc[j] * inv;
            a += __shfl_xor(a, 16);
            a += __shfl_xor(a, 32);
            acc[j] = a;
        }
        if (lane < 16) {
            float o[8];
#pragma unroll
            for (int j = 0; j < 8; j++) {
                float tv = acc[j] + conv_b[sub * 8 + j];
                o[j] = tv;
                s1[j] += tv;
                s2[j] = fmaf(tv, tv, s2[j]);
            }
            float* gp = g + (size_t)n * 128 + sub * 8;
            *(float4*)gp       = make_float4(o[0], o[1], o[2], o[3]);
            *(float4*)(gp + 4) = make_float4(o[4], o[5], o[6], o[7]);
        }
    }

    __shared__ float redA[4][128], redB[4][128];
    if (lane < 16) {
#pragma unroll
        for (int j = 0; j < 8; j++) {
            redA[wib][sub * 8 + j] = s1[j];
            redB[wib][sub * 8 + j] = s2[j];
        }
    }
    __syncthreads();
    int t = threadIdx.x;
    if (t < 128) {
        atomicAdd(&bnsum[t], redA[0][t] + redA[1][t] + redA[2][t] + redA[3][t]);
    } else {
        int c = t - 128;
        atomicAdd(&bnsum2[c], redB[0][c] + redB[1][c] + redB[2][c] + redB[3][c]);
    }
}

// ---------------- pooling + MLP head fused ----------------
__global__ __launch_bounds__(256) void pool_head(const short* __restrict__ hb,
                                                 const int* __restrict__ gstart,
                                                 const float* __restrict__ fc1W,
                                                 const float* __restrict__ fc1b,
                                                 const float* __restrict__ fc3W,
                                                 const float* __restrict__ fc3b,
                                                 float* __restrict__ out) {
    int gid = blockIdx.x, t = threadIdx.x;
    int lo = gstart[gid], hi = gstart[gid + 1];
    int c = t & 127, half = t >> 7;
    float s = 0.f;
    for (int n = lo + half; n < hi; n += 2)
        s += bf2f((unsigned short)hb[(size_t)n * 128 + c]);
    __shared__ float sh[256];
    __shared__ float hg[128], a1[128];
    sh[t] = s;
    __syncthreads();
    if (half == 0) {
        float cc = fmaxf((float)(hi - lo), 1.f);
        hg[c] = (sh[c] + sh[c + 128]) / cc;
    }
    __syncthreads();
    if (t < 128) {
        float v = fc1b[t];
        for (int c2 = 0; c2 < 128; c2++) v = fmaf(hg[c2], fc1W[c2 * 128 + t], v);
        a1[t] = fmaxf(v, 0.f);
    }
    __syncthreads();
    if (t < 16) {
        float o = fc3b[t];
        for (int j = 0; j < 128; j++) o = fmaf(a1[j], fc3W[j * 16 + t], o);
        out[gid * 16 + t] = o;
    }
}

extern "C" void kernel_launch(void* const* d_in, const int* in_sizes, int n_in,
                              void* d_out, int out_size, void* d_ws, size_t ws_size,
                              hipStream_t stream) {
    const float* x       = (const float*)d_in[0];
    const int*   ei      = (const int*)d_in[1];
    const int*   batch   = (const int*)d_in[2];
    const float* W       = (const float*)d_in[3];
    const float* att_src = (const float*)d_in[4];
    const float* att_dst = (const float*)d_in[5];
    const float* conv_b  = (const float*)d_in[6];
    const float* gamma   = (const float*)d_in[7];
    const float* beta    = (const float*)d_in[8];
    const float* sk_Win  = (const float*)d_in[9];
    const float* sk_bin  = (const float*)d_in[10];
    const float* sk_Wout = (const float*)d_in[11];
    const float* sk_bout = (const float*)d_in[12];
    const float* fc1_W   = (const float*)d_in[13];
    const float* fc1_b   = (const float*)d_in[14];
    const float* fc3_W   = (const float*)d_in[15];
    const float* fc3_b   = (const float*)d_in[16];
    float* out = (float*)d_out;
    const int* ei0 = ei;
    const int* ei1 = ei + N_EDGES;

    float* ws = (float*)d_ws;
    size_t o = 0;
    unsigned short* hfullb = (unsigned short*)(ws + o); o += (size_t)N_NODES * 256;  // bf16 [N,512]
    float* gbuf   = ws + o; o += (size_t)N_NODES * 128;
    short* hbA    = (short*)(ws + o); o += (size_t)N_NODES * 64;   // bf16 [N,128] ping
    short* hbB    = (short*)(ws + o); o += (size_t)N_NODES * 64;   // pong
    float* als    = ws + o; o += N_NODES * 4;
    float* ald    = ws + o; o += N_NODES * 4;
    float* bnsum  = ws + o; o += 768;      // 3 layers x (128 sum + 128 sumsq)
    short* wt_hi   = (short*)(ws + o); o += 98304;   // 3*512*128 shorts
    short* wint_hi = (short*)(ws + o); o += 24576;   // 3*128*128 shorts
    short* woutt_hi = (short*)(ws + o); o += 24576;
    int* gstart   = (int*)(ws + o); o += 132;
    int* deg      = (int*)(ws + o); o += N_NODES;
    int* rowptr   = (int*)(ws + o); o += N_NODES + 4;
    int* wofs     = (int*)(ws + o); o += N_NODES;
    int* scantmp  = (int*)(ws + o); o += N_NODES;
    int* blksum   = (int*)(ws + o); o += NBLK + 2;
    int* blkoff   = (int*)(ws + o); o += NBLK + 2;
    int* csr_src  = (int*)(ws + o); o += ETOT;

    prep_kernel<<<3028, 256, 0, stream>>>(W, sk_Win, sk_Wout, x, batch,
                                          wt_hi, wint_hi, woutt_hi, hbA, gstart);

    hipMemsetAsync(deg, 0, N_NODES * 4, stream);
    hipMemsetAsync(bnsum, 0, 768 * 4, stream);
    deg_kernel<<<(ETOT + 255) / 256, 256, 0, stream>>>(ei1, deg);
    scan1<<<NBLK, 256, 0, stream>>>(deg, scantmp, blksum);
    scan2<<<1, 128, 0, stream>>>(blksum, blkoff);
    scan3<<<NBLK, 256, 0, stream>>>(scantmp, blkoff, rowptr, wofs);
    scatter_kernel<<<(ETOT + 255) / 256, 256, 0, stream>>>(ei0, ei1, wofs, csr_src);

    // layer 0 conv
    gemm_conv<<<dim3(469, 4), 256, 0, stream>>>(hbA, wt_hi, att_src, att_dst, hfullb, als, ald);
    gat_gather<<<1024, 256, 0, stream>>>(rowptr, csr_src, als, ald, hfullb,
                                         conv_b, gbuf, bnsum, bnsum + 128);
    // fused skip(0) + conv(1)
    skip_conv<<<469, 256, 0, stream>>>(hbA, gbuf, bnsum, gamma, beta,
                                       wint_hi, woutt_hi, sk_bin, sk_bout,
                                       wt_hi + 65536, att_src + 512, att_dst + 512,
                                       hbB, hfullb, als, ald);
    gat_gather<<<1024, 256, 0, stream>>>(rowptr, csr_src, als, ald, hfullb,
                                         conv_b + 128, gbuf, bnsum + 256, bnsum + 384);
    // fused skip(1) + conv(2)
    skip_conv<<<469, 256, 0, stream>>>(hbB, gbuf, bnsum + 256, gamma + 128, beta + 128,
                                       wint_hi + 16384, woutt_hi + 16384, sk_bin + 128, sk_bout + 128,
                                       wt_hi + 131072, att_src + 1024, att_dst + 1024,
                                       hbA, hfullb, als, ald);
    gat_gather<<<1024, 256, 0, stream>>>(rowptr, csr_src, als, ald, hfullb,
                                         conv_b + 256, gbuf, bnsum + 512, bnsum + 640);
    // last skip
    skip_gate<<<dim3(469, 2), 256, 0, stream>>>(hbA, gbuf, bnsum + 512, gamma + 256, beta + 256,
                                                wint_hi + 32768, woutt_hi + 32768,
                                                sk_bin + 256, sk_bout + 256, hbB);

    pool_head<<<NGRAPH, 256, 0, stream>>>(hbB, gstart, fc1_W, fc1_b, fc3_W, fc3_b, out);
}

// Round 14
// 389.996 us; speedup vs baseline: 2.3829x; 1.0599x over previous
//
#include <hip/hip_runtime.h>
#include <hip/hip_bf16.h>

#define N_NODES 30000
#define N_EDGES 240000
#define ETOT    (N_EDGES + N_NODES)   // 270000 (self loops appended)
#define NGRAPH  128
#define NBLK    118                   // ceil(30000/256)
#define NWAVES  4096

typedef __attribute__((ext_vector_type(8))) short bf16x8;
typedef __attribute__((ext_vector_type(4))) short bf16x4;
typedef __attribute__((ext_vector_type(4))) float f32x4;

__device__ __forceinline__ unsigned short f2bf(float f) {
    unsigned u = __float_as_uint(f);
    u += 0x7fff + ((u >> 16) & 1);        // round-to-nearest-even
    return (unsigned short)(u >> 16);
}
__device__ __forceinline__ float bf2f(unsigned short h) {
    return __uint_as_float(((unsigned)h) << 16);
}

// ---------- merged prep: weights->bf16T, x->bf16, bounds, zero deg/bnsum ----------
__global__ __launch_bounds__(256) void prep_kernel(const float* __restrict__ W,
                                                   const float* __restrict__ Win,
                                                   const float* __restrict__ Wout,
                                                   const float* __restrict__ x,
                                                   const int* __restrict__ batch,
                                                   short* __restrict__ wt_hi,
                                                   short* __restrict__ wint_hi,
                                                   short* __restrict__ woutt_hi,
                                                   short* __restrict__ xb,
                                                   int* __restrict__ gstart,
                                                   int* __restrict__ deg,
                                                   float* __restrict__ bnsum) {
    int i = blockIdx.x * 256 + threadIdx.x;
    if (i < 196608) {                       // 3*512*128
        int l = i >> 16, r = i & 65535;
        int n = r >> 7, k = r & 127;
        wt_hi[i] = (short)f2bf(W[(size_t)l * 65536 + k * 512 + n]);
    } else if (i < 245760) {                // + 3*128*128
        int j = i - 196608;
        int l = j >> 14, r = j & 16383;
        int n = r >> 7, k = r & 127;
        wint_hi[j] = (short)f2bf(Win[(size_t)l * 16384 + k * 128 + n]);
    } else if (i < 294912) {
        int j = i - 245760;
        int l = j >> 14, r = j & 16383;
        int n = r >> 7, k = r & 127;
        woutt_hi[j] = (short)f2bf(Wout[(size_t)l * 16384 + k * 128 + n]);
    } else if (i < 774912) {                // x -> bf16, 8 floats per thread
        int j = i - 294912;
        const float4* p = (const float4*)x + (size_t)j * 2;
        float4 v0 = p[0], v1 = p[1];
        bf16x8 hv;
        hv[0] = (short)f2bf(v0.x); hv[1] = (short)f2bf(v0.y);
        hv[2] = (short)f2bf(v0.z); hv[3] = (short)f2bf(v0.w);
        hv[4] = (short)f2bf(v1.x); hv[5] = (short)f2bf(v1.y);
        hv[6] = (short)f2bf(v1.z); hv[7] = (short)f2bf(v1.w);
        *(bf16x8*)(xb + (size_t)j * 8) = hv;
    } else if (i < 775041) {                // graph segment bounds (129)
        int t = i - 774912;
        int lo = 0, hi = N_NODES;
        while (lo < hi) { int mid = (lo + hi) >> 1; if (batch[mid] < t) lo = mid + 1; else hi = mid; }
        gstart[t] = lo;
    } else if (i < 805041) {                // zero deg
        deg[i - 775041] = 0;
    } else if (i < 805809) {                // zero bnsum (768)
        bnsum[i - 805041] = 0.f;
    }
}

// ---------- conv GEMM (bf16 x bf16) + logits + coalesced store (layer 0 only) ----
__global__ __launch_bounds__(256) void gemm_conv(const short* __restrict__ Ab,
                                                 const short* __restrict__ Bth,
                                                 const float* __restrict__ att_s,
                                                 const float* __restrict__ att_d,
                                                 unsigned short* __restrict__ hfullb,
                                                 float* __restrict__ als,
                                                 float* __restrict__ ald) {
    __shared__ short As_h[64 * 136];
    __shared__ float red_s[2][64], red_d[2][64];
    const int bm = blockIdx.x * 64;
    const int hd = blockIdx.y;
    const int bn = hd * 128;
    const int t  = threadIdx.x;
#pragma unroll
    for (int i = 0; i < 4; i++) {
        int idx8 = t + i * 256;
        int row = idx8 >> 4, c8 = (idx8 & 15) << 3;
        bf16x8 vh = {};
        if (bm + row < N_NODES)
            vh = *(const bf16x8*)(Ab + (size_t)(bm + row) * 128 + c8);
        *(bf16x8*)(As_h + row * 136 + c8) = vh;
    }
    __syncthreads();

    const int w = t >> 6, lane = t & 63;
    const int wr = w >> 1, wc = w & 1;
    const int lr = lane & 15, lg = lane >> 4;
    f32x4 acc[2][4] = {};
    const size_t bofs0 = (size_t)(bn + wc * 64 + lr) * 128 + lg * 8;
#pragma unroll
    for (int kk = 0; kk < 4; kk++) {
        bf16x8 ah[2], bh[4];
#pragma unroll
        for (int ni = 0; ni < 4; ni++) {
            size_t o = bofs0 + (size_t)ni * 16 * 128 + kk * 32;
            bh[ni] = *(const bf16x8*)(Bth + o);
        }
        int ko = kk * 32 + lg * 8;
#pragma unroll
        for (int mi = 0; mi < 2; mi++) {
            int r = wr * 32 + mi * 16 + lr;
            ah[mi] = *(const bf16x8*)(As_h + r * 136 + ko);
        }
#pragma unroll
        for (int mi = 0; mi < 2; mi++)
#pragma unroll
            for (int ni = 0; ni < 4; ni++)
                acc[mi][ni] = __builtin_amdgcn_mfma_f32_16x16x32_bf16(ah[mi], bh[ni], acc[mi][ni], 0, 0, 0);
    }
    float as_c[4], ad_c[4];
#pragma unroll
    for (int ni = 0; ni < 4; ni++) {
        int cc = wc * 64 + ni * 16 + lr;
        as_c[ni] = att_s[hd * 128 + cc];
        ad_c[ni] = att_d[hd * 128 + cc];
    }
#pragma unroll
    for (int mi = 0; mi < 2; mi++) {
#pragma unroll
        for (int r = 0; r < 4; r++) {
            float ps = 0.f, pd = 0.f;
#pragma unroll
            for (int ni = 0; ni < 4; ni++) {
                ps = fmaf(acc[mi][ni][r], as_c[ni], ps);
                pd = fmaf(acc[mi][ni][r], ad_c[ni], pd);
            }
#pragma unroll
            for (int off = 1; off < 16; off <<= 1) {
                ps += __shfl_xor(ps, off);
                pd += __shfl_xor(pd, off);
            }
            if (lr == 0) {
                int row = wr * 32 + mi * 16 + lg * 4 + r;
                red_s[wc][row] = ps;
                red_d[wc][row] = pd;
            }
        }
    }
    __syncthreads();
#pragma unroll
    for (int mi = 0; mi < 2; mi++)
#pragma unroll
        for (int ni = 0; ni < 4; ni++) {
            int nl = wc * 64 + ni * 16 + lr;
#pragma unroll
            for (int r = 0; r < 4; r++) {
                int row = wr * 32 + mi * 16 + lg * 4 + r;
                As_h[row * 136 + nl] = (short)f2bf(acc[mi][ni][r]);
            }
        }
    if (t < 64) {
        int m = bm + t;
        if (m < N_NODES) als[m * 4 + hd] = red_s[0][t] + red_s[1][t];
    } else if (t < 128) {
        int tt = t - 64;
        int m = bm + tt;
        if (m < N_NODES) ald[m * 4 + hd] = red_d[0][tt] + red_d[1][tt];
    }
    __syncthreads();
#pragma unroll
    for (int i2 = 0; i2 < 4; i2++) {
        int idx8 = t + i2 * 256;
        int row = idx8 >> 4, c8 = (idx8 & 15) << 3;
        int m = bm + row;
        if (m < N_NODES)
            *(bf16x8*)(hfullb + (size_t)m * 512 + bn + c8) = *(const bf16x8*)(As_h + row * 136 + c8);
    }
}

// ---------- fused skip(l) + conv(l+1): one 64-row block does both ----------
__global__ __launch_bounds__(256) void skip_conv(const short* __restrict__ hinb,
                                                 const float* __restrict__ g,
                                                 const float* __restrict__ bnsum,
                                                 const float* __restrict__ gamma,
                                                 const float* __restrict__ beta,
                                                 const short* __restrict__ w1h,
                                                 const short* __restrict__ w2h,
                                                 const float* __restrict__ bin,
                                                 const float* __restrict__ bout,
                                                 const short* __restrict__ wtn,    // conv W^T (l+1) [512][128]
                                                 const float* __restrict__ att_s,  // (l+1)
                                                 const float* __restrict__ att_d,
                                                 short* __restrict__ houtb,
                                                 unsigned short* __restrict__ hfullb,
                                                 float* __restrict__ als,
                                                 float* __restrict__ ald) {
    __shared__ short A1h[64 * 136], A2h[64 * 136];
    __shared__ float bnp_s[256];
    __shared__ float redS[4][64], redD[4][64];
    const int bm = blockIdx.x * 64;
    const int t  = threadIdx.x;
    if (t < 128) {
        float inv = 1.f / (float)N_NODES;
        float mu  = bnsum[t] * inv;
        float var = bnsum[128 + t] * inv - mu * mu;
        float rs  = rsqrtf(var + 1e-5f);
        float sc  = gamma[t] * rs;
        bnp_s[t]       = sc;
        bnp_s[128 + t] = beta[t] - mu * sc;
    }
    __syncthreads();
#pragma unroll
    for (int i = 0; i < 4; i++) {
        int idx8 = t + i * 256;
        int row = idx8 >> 4, c8 = (idx8 & 15) << 3;
        bf16x8 vh = {};
        if (bm + row < N_NODES)
            vh = *(const bf16x8*)(hinb + (size_t)(bm + row) * 128 + c8);
        *(bf16x8*)(A1h + row * 136 + c8) = vh;
    }
#pragma unroll
    for (int i = 0; i < 8; i++) {
        int idx4 = t + i * 256;
        int row = idx4 >> 5, c4 = (idx4 & 31) << 2;
        float4 v2 = make_float4(0.f, 0.f, 0.f, 0.f);
        if (bm + row < N_NODES) {
            float4 gv = *(const float4*)(g + (size_t)(bm + row) * 128 + c4);
            v2.x = fmaf(bnp_s[c4 + 0], gv.x, bnp_s[128 + c4 + 0]);
            v2.y = fmaf(bnp_s[c4 + 1], gv.y, bnp_s[128 + c4 + 1]);
            v2.z = fmaf(bnp_s[c4 + 2], gv.z, bnp_s[128 + c4 + 2]);
            v2.w = fmaf(bnp_s[c4 + 3], gv.w, bnp_s[128 + c4 + 3]);
        }
        *(bf16x4*)(A2h + row * 136 + c4) = (bf16x4){(short)f2bf(v2.x), (short)f2bf(v2.y),
                                                    (short)f2bf(v2.z), (short)f2bf(v2.w)};
    }
    __syncthreads();

    const int w = t >> 6, lane = t & 63;
    const int wr = w >> 1, wc = w & 1;
    const int lr = lane & 15, lg = lane >> 4;

    // phase A: P = hin@W1 + bn(g)@W2 over full 64x128; gate+relu
    {
        f32x4 acc[2][4] = {};
        const size_t bo = (size_t)(wc * 64 + lr) * 128 + lg * 8;
#pragma unroll
        for (int kk = 0; kk < 4; kk++) {
            bf16x8 a1[2], a2[2], b1[4], b2[4];
#pragma unroll
            for (int ni = 0; ni < 4; ni++) {
                size_t o = bo + (size_t)ni * 2048 + kk * 32;
                b1[ni] = *(const bf16x8*)(w1h + o);
                b2[ni] = *(const bf16x8*)(w2h + o);
            }
            int ko = kk * 32 + lg * 8;
#pragma unroll
            for (int mi = 0; mi < 2; mi++) {
                int r = wr * 32 + mi * 16 + lr;
                a1[mi] = *(const bf16x8*)(A1h + r * 136 + ko);
                a2[mi] = *(const bf16x8*)(A2h + r * 136 + ko);
            }
#pragma unroll
            for (int mi = 0; mi < 2; mi++)
#pragma unroll
                for (int ni = 0; ni < 4; ni++) {
                    acc[mi][ni] = __builtin_amdgcn_mfma_f32_16x16x32_bf16(a1[mi], b1[ni], acc[mi][ni], 0, 0, 0);
                    acc[mi][ni] = __builtin_amdgcn_mfma_f32_16x16x32_bf16(a2[mi], b2[ni], acc[mi][ni], 0, 0, 0);
                }
        }
#pragma unroll
        for (int mi = 0; mi < 2; mi++)
#pragma unroll
            for (int ni = 0; ni < 4; ni++) {
                int n = wc * 64 + ni * 16 + lr;
                float bsum = bin[n] + bout[n];
                float sc = bnp_s[n], shb = bnp_s[128 + n];
#pragma unroll
                for (int r = 0; r < 4; r++) {
                    int lrow = wr * 32 + mi * 16 + lg * 4 + r;
                    int m = bm + lrow;
                    float gv = (m < N_NODES) ? g[(size_t)m * 128 + n] : 0.f;
                    float hbnv = fmaf(sc, gv, shb);
                    float hv   = bf2f((unsigned short)A1h[lrow * 136 + n]);
                    float gt   = 1.f / (1.f + __expf(-(acc[mi][ni][r] + bsum)));
                    acc[mi][ni][r] = fmaxf(gt * hbnv + (1.f - gt) * hv, 0.f);
                }
            }
        __syncthreads();
#pragma unroll
        for (int mi = 0; mi < 2; mi++)
#pragma unroll
            for (int ni = 0; ni < 4; ni++) {
                int n = wc * 64 + ni * 16 + lr;
#pragma unroll
                for (int r = 0; r < 4; r++) {
                    int lrow = wr * 32 + mi * 16 + lg * 4 + r;
                    A1h[lrow * 136 + n] = (short)f2bf(acc[mi][ni][r]);
                }
            }
        __syncthreads();
#pragma unroll
        for (int i2 = 0; i2 < 4; i2++) {
            int idx8 = t + i2 * 256;
            int row = idx8 >> 4, c8 = (idx8 & 15) << 3;
            int m = bm + row;
            if (m < N_NODES)
                *(bf16x8*)(houtb + (size_t)m * 128 + c8) = *(const bf16x8*)(A1h + row * 136 + c8);
        }
    }

    // phase B: conv(l+1) on hout tile in A1h; wave = head
    f32x4 c2[4][8] = {};
    const int hd = w;
    const size_t bo2 = (size_t)(hd * 128 + lr) * 128 + lg * 8;
#pragma unroll
    for (int kk = 0; kk < 4; kk++) {
        bf16x8 ah2[4], bh2[8];
#pragma unroll
        for (int ni = 0; ni < 8; ni++)
            bh2[ni] = *(const bf16x8*)(wtn + bo2 + (size_t)ni * 2048 + kk * 32);
        int ko = kk * 32 + lg * 8;
#pragma unroll
        for (int mi = 0; mi < 4; mi++)
            ah2[mi] = *(const bf16x8*)(A1h + (mi * 16 + lr) * 136 + ko);
#pragma unroll
        for (int mi = 0; mi < 4; mi++)
#pragma unroll
            for (int ni = 0; ni < 8; ni++)
                c2[mi][ni] = __builtin_amdgcn_mfma_f32_16x16x32_bf16(ah2[mi], bh2[ni], c2[mi][ni], 0, 0, 0);
    }
    {
        float asc[8], adc[8];
#pragma unroll
        for (int ni = 0; ni < 8; ni++) {
            int cc = ni * 16 + lr;
            asc[ni] = att_s[hd * 128 + cc];
            adc[ni] = att_d[hd * 128 + cc];
        }
#pragma unroll
        for (int mi = 0; mi < 4; mi++)
#pragma unroll
            for (int r = 0; r < 4; r++) {
                float ps = 0.f, pd = 0.f;
#pragma unroll
                for (int ni = 0; ni < 8; ni++) {
                    ps = fmaf(c2[mi][ni][r], asc[ni], ps);
                    pd = fmaf(c2[mi][ni][r], adc[ni], pd);
                }
#pragma unroll
                for (int off = 1; off < 16; off <<= 1) {
                    ps += __shfl_xor(ps, off);
                    pd += __shfl_xor(pd, off);
                }
                if (lr == 0) {
                    int row = mi * 16 + lg * 4 + r;
                    redS[hd][row] = ps;
                    redD[hd][row] = pd;
                }
            }
    }
    __syncthreads();
    if (w < 2) {
        short* dst = (w == 0) ? A1h : A2h;
#pragma unroll
        for (int mi = 0; mi < 4; mi++)
#pragma unroll
            for (int ni = 0; ni < 8; ni++)
#pragma unroll
                for (int r = 0; r < 4; r++)
                    dst[(mi * 16 + lg * 4 + r) * 136 + ni * 16 + lr] = (short)f2bf(c2[mi][ni][r]);
    }
    {
        int hd2 = t >> 6, row = t & 63;
        int m = bm + row;
        if (m < N_NODES) {
            als[m * 4 + hd2] = redS[hd2][row];
            ald[m * 4 + hd2] = redD[hd2][row];
        }
    }
    __syncthreads();
#pragma unroll
    for (int it = 0; it < 8; it++) {
        int idx = t + it * 256;
        int row = idx >> 5, c8 = (idx & 31) << 3;
        int m = bm + row;
        if (m < N_NODES) {
            const short* src = (c8 < 128) ? A1h : A2h;
            *(bf16x8*)(hfullb + (size_t)m * 512 + c8) = *(const bf16x8*)(src + row * 136 + (c8 & 127));
        }
    }
    __syncthreads();
    if (w >= 2) {
        short* dst = (w == 2) ? A1h : A2h;
#pragma unroll
        for (int mi = 0; mi < 4; mi++)
#pragma unroll
            for (int ni = 0; ni < 8; ni++)
#pragma unroll
                for (int r = 0; r < 4; r++)
                    dst[(mi * 16 + lg * 4 + r) * 136 + ni * 16 + lr] = (short)f2bf(c2[mi][ni][r]);
    }
    __syncthreads();
#pragma unroll
    for (int it = 0; it < 8; it++) {
        int idx = t + it * 256;
        int row = idx >> 5, c8 = (idx & 31) << 3;
        int m = bm + row;
        if (m < N_NODES) {
            const short* src = (c8 < 128) ? A1h : A2h;
            *(bf16x8*)(hfullb + (size_t)m * 512 + 256 + c8) = *(const bf16x8*)(src + row * 136 + (c8 & 127));
        }
    }
}

// ---------- plain skip (last layer) ----------
__global__ __launch_bounds__(256) void skip_gate(const short* __restrict__ hinb,
                                                 const float* __restrict__ g,
                                                 const float* __restrict__ bnsum,
                                                 const float* __restrict__ gamma,
                                                 const float* __restrict__ beta,
                                                 const short* __restrict__ w1h,
                                                 const short* __restrict__ w2h,
                                                 const float* __restrict__ bin, const float* __restrict__ bout,
                                                 short* __restrict__ houtb) {
    __shared__ short A1h[64 * 136], A2h[64 * 136], A2l[64 * 136];
    __shared__ float bnp_s[256];
    const int bm = blockIdx.x * 64;
    const int bn = blockIdx.y * 64;
    const int t  = threadIdx.x;
    if (t < 128) {
        float inv = 1.f / (float)N_NODES;
        float mu  = bnsum[t] * inv;
        float var = bnsum[128 + t] * inv - mu * mu;
        float rs  = rsqrtf(var + 1e-5f);
        float sc  = gamma[t] * rs;
        bnp_s[t]       = sc;
        bnp_s[128 + t] = beta[t] - mu * sc;
    }
    __syncthreads();
#pragma unroll
    for (int i = 0; i < 4; i++) {
        int idx8 = t + i * 256;
        int row = idx8 >> 4, c8 = (idx8 & 15) << 3;
        bf16x8 vh = {};
        if (bm + row < N_NODES)
            vh = *(const bf16x8*)(hinb + (size_t)(bm + row) * 128 + c8);
        *(bf16x8*)(A1h + row * 136 + c8) = vh;
    }
#pragma unroll
    for (int i = 0; i < 8; i++) {
        int idx4 = t + i * 256;
        int row = idx4 >> 5, c4 = (idx4 & 31) << 2;
        float4 v2 = make_float4(0.f, 0.f, 0.f, 0.f);
        if (bm + row < N_NODES) {
            float4 gv = *(const float4*)(g + (size_t)(bm + row) * 128 + c4);
            v2.x = fmaf(bnp_s[c4 + 0], gv.x, bnp_s[128 + c4 + 0]);
            v2.y = fmaf(bnp_s[c4 + 1], gv.y, bnp_s[128 + c4 + 1]);
            v2.z = fmaf(bnp_s[c4 + 2], gv.z, bnp_s[128 + c4 + 2]);
            v2.w = fmaf(bnp_s[c4 + 3], gv.w, bnp_s[128 + c4 + 3]);
        }
        unsigned short b0 = f2bf(v2.x), b1 = f2bf(v2.y), b2 = f2bf(v2.z), b3 = f2bf(v2.w);
        *(bf16x4*)(A2h + row * 136 + c4) = (bf16x4){(short)b0, (short)b1, (short)b2, (short)b3};
        *(bf16x4*)(A2l + row * 136 + c4) = (bf16x4){(short)f2bf(v2.x - bf2f(b0)), (short)f2bf(v2.y - bf2f(b1)),
                                                    (short)f2bf(v2.z - bf2f(b2)), (short)f2bf(v2.w - bf2f(b3))};
    }
    __syncthreads();

    const int w = t >> 6, lane = t & 63;
    const int wr = w >> 1, wc = w & 1;
    const int lr = lane & 15, lg = lane >> 4;
    f32x4 acc[2][2] = {};
    const size_t bofs0 = (size_t)(bn + wc * 32 + lr) * 128 + lg * 8;
#pragma unroll
    for (int kk = 0; kk < 4; kk++) {
        bf16x8 a1f[2], a2f[2], b1h[2], b2h[2];
#pragma unroll
        for (int ni = 0; ni < 2; ni++) {
            size_t o = bofs0 + (size_t)ni * 16 * 128 + kk * 32;
            b1h[ni] = *(const bf16x8*)(w1h + o);
            b2h[ni] = *(const bf16x8*)(w2h + o);
        }
        int ko = kk * 32 + lg * 8;
#pragma unroll
        for (int mi = 0; mi < 2; mi++) {
            int r = wr * 32 + mi * 16 + lr;
            a1f[mi] = *(const bf16x8*)(A1h + r * 136 + ko);
            a2f[mi] = *(const bf16x8*)(A2h + r * 136 + ko);
        }
#pragma unroll
        for (int mi = 0; mi < 2; mi++)
#pragma unroll
            for (int ni = 0; ni < 2; ni++) {
                acc[mi][ni] = __builtin_amdgcn_mfma_f32_16x16x32_bf16(a1f[mi], b1h[ni], acc[mi][ni], 0, 0, 0);
                acc[mi][ni] = __builtin_amdgcn_mfma_f32_16x16x32_bf16(a2f[mi], b2h[ni], acc[mi][ni], 0, 0, 0);
            }
    }
#pragma unroll
    for (int mi = 0; mi < 2; mi++) {
#pragma unroll
        for (int ni = 0; ni < 2; ni++) {
            int n = bn + wc * 32 + ni * 16 + lr;
            float bsum = bin[n] + bout[n];
#pragma unroll
            for (int r = 0; r < 4; r++) {
                int lrow = wr * 32 + mi * 16 + lg * 4 + r;
                float hbnv = bf2f((unsigned short)A2h[lrow * 136 + n]) + bf2f((unsigned short)A2l[lrow * 136 + n]);
                float hv   = bf2f((unsigned short)A1h[lrow * 136 + n]);
                float gt   = 1.f / (1.f + __expf(-(acc[mi][ni][r] + bsum)));
                acc[mi][ni][r] = fmaxf(gt * hbnv + (1.f - gt) * hv, 0.f);
            }
        }
    }
    __syncthreads();
#pragma unroll
    for (int mi = 0; mi < 2; mi++)
#pragma unroll
        for (int ni = 0; ni < 2; ni++) {
            int n = bn + wc * 32 + ni * 16 + lr;
#pragma unroll
            for (int r = 0; r < 4; r++) {
                int lrow = wr * 32 + mi * 16 + lg * 4 + r;
                A1h[lrow * 136 + n] = (short)f2bf(acc[mi][ni][r]);
            }
        }
    __syncthreads();
#pragma unroll
    for (int i2 = 0; i2 < 2; i2++) {
        int idx8 = t + i2 * 256;
        int row = idx8 >> 3, c8 = (idx8 & 7) << 3;
        int m = bm + row;
        if (m < N_NODES)
            *(bf16x8*)(houtb + (size_t)m * 128 + bn + c8) = *(const bf16x8*)(A1h + row * 136 + bn + c8);
    }
}

// ---------------- CSR build ----------------
__global__ __launch_bounds__(256) void deg_kernel(const int* __restrict__ ei1,
                                                  int* __restrict__ deg) {
    int e = blockIdx.x * 256 + threadIdx.x;
    if (e >= ETOT) return;
    int d = (e < N_EDGES) ? ei1[e] : (e - N_EDGES);
    atomicAdd(&deg[d], 1);
}

__global__ __launch_bounds__(256) void scan1(const int* __restrict__ deg,
                                             int* __restrict__ tmp,
                                             int* __restrict__ blksum) {
    int i = blockIdx.x * 256 + threadIdx.x;
    int v = (i < N_NODES) ? deg[i] : 0;
    __shared__ int sh[256];
    sh[threadIdx.x] = v;
    __syncthreads();
    int acc = v;
    for (int off = 1; off < 256; off <<= 1) {
        int u = (threadIdx.x >= off) ? sh[threadIdx.x - off] : 0;
        __syncthreads();
        acc += u;
        sh[threadIdx.x] = acc;
        __syncthreads();
    }
    if (i < N_NODES) tmp[i] = acc - v;     // exclusive within block
    if (threadIdx.x == 255) blksum[blockIdx.x] = acc;
}

__global__ void scan2(const int* __restrict__ blksum, int* __restrict__ blkoff) {
    int t = threadIdx.x;                   // 128 threads >= NBLK
    int v = (t < NBLK) ? blksum[t] : 0;
    __shared__ int sh[128];
    sh[t] = v;
    __syncthreads();
    int acc = v;
    for (int off = 1; off < 128; off <<= 1) {
        int u = (t >= off) ? sh[t - off] : 0;
        __syncthreads();
        acc += u;
        sh[t] = acc;
        __syncthreads();
    }
    if (t < NBLK) blkoff[t] = acc - v;     // exclusive block offset
}

__global__ __launch_bounds__(256) void scan3(const int* __restrict__ tmp,
                                             const int* __restrict__ blkoff,
                                             int* __restrict__ rowptr,
                                             int* __restrict__ wofs) {
    int i = blockIdx.x * 256 + threadIdx.x;
    if (i == 0) rowptr[N_NODES] = ETOT;
    if (i < N_NODES) {
        int r = tmp[i] + blkoff[blockIdx.x];
        rowptr[i] = r;
        wofs[i]   = r;
    }
}

// edge-balanced wave partition: wave w starts at first node whose rowptr >= w*ETOT/NWAVES
__global__ __launch_bounds__(256) void wpart_kernel(const int* __restrict__ rowptr,
                                                    int* __restrict__ wstart) {
    int wid = blockIdx.x * 256 + threadIdx.x;
    if (wid > NWAVES) return;
    if (wid == NWAVES) { wstart[NWAVES] = N_NODES; return; }
    int target = (int)(((long)wid * ETOT) / NWAVES);
    int lo = 0, hi = N_NODES;
    while (lo < hi) { int mid = (lo + hi) >> 1; if (rowptr[mid] < target) lo = mid + 1; else hi = mid; }
    wstart[wid] = lo;
}

__global__ __launch_bounds__(256) void scatter_kernel(const int* __restrict__ ei0,
                                                      const int* __restrict__ ei1,
                                                      int* __restrict__ wofs,
                                                      int* __restrict__ csr_src) {
    int e = blockIdx.x * 256 + threadIdx.x;
    if (e >= ETOT) return;
    int s = (e < N_EDGES) ? ei0[e] : (e - N_EDGES);
    int d = (e < N_EDGES) ? ei1[e] : (e - N_EDGES);
    int pos = atomicAdd(&wofs[d], 1);
    csr_src[pos] = s;
}

// ---------------- fused gather: single pass, edge-balanced wave ranges ----------------
__global__ __launch_bounds__(256) void gat_gather(const int* __restrict__ rowptr,
                                                  const int* __restrict__ wstart,
                                                  const int* __restrict__ csr_src,
                                                  const float* __restrict__ al_s,
                                                  const float* __restrict__ al_d,
                                                  const unsigned short* __restrict__ hfullb,
                                                  const float* __restrict__ conv_b,
                                                  float* __restrict__ g,
                                                  float* __restrict__ bnsum,
                                                  float* __restrict__ bnsum2) {
    const int lane = threadIdx.x & 63;
    const int wib  = threadIdx.x >> 6;
    const int gwid = blockIdx.x * 4 + wib;
    const int h    = lane >> 4;
    const int sub  = lane & 15;
    float s1[8] = {}, s2[8] = {};

    const int n0 = wstart[gwid], n1 = wstart[gwid + 1];
    for (int n = n0; n < n1; n++) {
        const int e0 = rowptr[n], e1 = rowptr[n + 1];
        const float ald_h = al_d[n * 4 + h];

        float acc[8] = {};
        float zs = 0.f;
        int i = e0;
        for (; i + 3 < e1; i += 4) {
            int sA = csr_src[i], sB = csr_src[i + 1], sC = csr_src[i + 2], sD = csr_src[i + 3];
            bf16x8 ha = *(const bf16x8*)(hfullb + (size_t)sA * 512 + lane * 8);
            bf16x8 hb = *(const bf16x8*)(hfullb + (size_t)sB * 512 + lane * 8);
            bf16x8 hc = *(const bf16x8*)(hfullb + (size_t)sC * 512 + lane * 8);
            bf16x8 hd = *(const bf16x8*)(hfullb + (size_t)sD * 512 + lane * 8);
            float vA = al_s[sA * 4 + h] + ald_h; vA = (vA > 0.f) ? vA : 0.2f * vA;
            float vB = al_s[sB * 4 + h] + ald_h; vB = (vB > 0.f) ? vB : 0.2f * vB;
            float vC = al_s[sC * 4 + h] + ald_h; vC = (vC > 0.f) ? vC : 0.2f * vC;
            float vD = al_s[sD * 4 + h] + ald_h; vD = (vD > 0.f) ? vD : 0.2f * vD;
            float exA = __expf(vA), exB = __expf(vB), exC = __expf(vC), exD = __expf(vD);
            zs += (exA + exB) + (exC + exD);
#pragma unroll
            for (int j = 0; j < 8; j++) {
                float a = fmaf(exA, bf2f((unsigned short)ha[j]), acc[j]);
                a = fmaf(exB, bf2f((unsigned short)hb[j]), a);
                a = fmaf(exC, bf2f((unsigned short)hc[j]), a);
                acc[j] = fmaf(exD, bf2f((unsigned short)hd[j]), a);
            }
        }
        for (; i < e1; i++) {
            int sA = csr_src[i];
            bf16x8 ha = *(const bf16x8*)(hfullb + (size_t)sA * 512 + lane * 8);
            float vA = al_s[sA * 4 + h] + ald_h; vA = (vA > 0.f) ? vA : 0.2f * vA;
            float exA = __expf(vA);
            zs += exA;
#pragma unroll
            for (int j = 0; j < 8; j++)
                acc[j] = fmaf(exA, bf2f((unsigned short)ha[j]), acc[j]);
        }

        float inv = 0.25f / (zs + 1e-16f);
#pragma unroll
        for (int j = 0; j < 8; j++) {
            float a = acc[j] * inv;
            a += __shfl_xor(a, 16);
            a += __shfl_xor(a, 32);
            acc[j] = a;
        }
        if (lane < 16) {
            float o[8];
#pragma unroll
            for (int j = 0; j < 8; j++) {
                float tv = acc[j] + conv_b[sub * 8 + j];
                o[j] = tv;
                s1[j] += tv;
                s2[j] = fmaf(tv, tv, s2[j]);
            }
            float* gp = g + (size_t)n * 128 + sub * 8;
            *(float4*)gp       = make_float4(o[0], o[1], o[2], o[3]);
            *(float4*)(gp + 4) = make_float4(o[4], o[5], o[6], o[7]);
        }
    }

    __shared__ float redA[4][128], redB[4][128];
    if (lane < 16) {
#pragma unroll
        for (int j = 0; j < 8; j++) {
            redA[wib][sub * 8 + j] = s1[j];
            redB[wib][sub * 8 + j] = s2[j];
        }
    }
    __syncthreads();
    int t = threadIdx.x;
    if (t < 128) {
        atomicAdd(&bnsum[t], redA[0][t] + redA[1][t] + redA[2][t] + redA[3][t]);
    } else {
        int c = t - 128;
        atomicAdd(&bnsum2[c], redB[0][c] + redB[1][c] + redB[2][c] + redB[3][c]);
    }
}

// ---------------- pooling + MLP head fused (1024 threads) ----------------
__global__ __launch_bounds__(1024) void pool_head(const short* __restrict__ hb,
                                                  const int* __restrict__ gstart,
                                                  const float* __restrict__ fc1W,
                                                  const float* __restrict__ fc1b,
                                                  const float* __restrict__ fc3W,
                                                  const float* __restrict__ fc3b,
                                                  float* __restrict__ out) {
    int gid = blockIdx.x, t = threadIdx.x;
    int lo = gstart[gid], hi = gstart[gid + 1];
    int c = t & 127, q = t >> 7;           // 8 row groups
    float s = 0.f;
    for (int n = lo + q; n < hi; n += 8)
        s += bf2f((unsigned short)hb[(size_t)n * 128 + c]);
    __shared__ float sh[1024];
    __shared__ float hg[128], a1[128];
    sh[t] = s;
    __syncthreads();
    if (t < 128) {
        float cc = fmaxf((float)(hi - lo), 1.f);
        float tot = 0.f;
#pragma unroll
        for (int q2 = 0; q2 < 8; q2++) tot += sh[q2 * 128 + t];
        hg[t] = tot / cc;
    }
    __syncthreads();
    {
        int oc = t & 127, ch = t >> 7;     // 8 chunks of 16 k-values
        float v = 0.f;
#pragma unroll
        for (int k = 0; k < 16; k++) {
            int c2 = ch * 16 + k;
            v = fmaf(hg[c2], fc1W[c2 * 128 + oc], v);
        }
        sh[t] = v;
    }
    __syncthreads();
    if (t < 128) {
        float v = fc1b[t];
#pragma unroll
        for (int q2 = 0; q2 < 8; q2++) v += sh[q2 * 128 + t];
        a1[t] = fmaxf(v, 0.f);
    }
    __syncthreads();
    if (t < 16) {
        float o = fc3b[t];
        for (int j = 0; j < 128; j++) o = fmaf(a1[j], fc3W[j * 16 + t], o);
        out[gid * 16 + t] = o;
    }
}

extern "C" void kernel_launch(void* const* d_in, const int* in_sizes, int n_in,
                              void* d_out, int out_size, void* d_ws, size_t ws_size,
                              hipStream_t stream) {
    const float* x       = (const float*)d_in[0];
    const int*   ei      = (const int*)d_in[1];
    const int*   batch   = (const int*)d_in[2];
    const float* W       = (const float*)d_in[3];
    const float* att_src = (const float*)d_in[4];
    const float* att_dst = (const float*)d_in[5];
    const float* conv_b  = (const float*)d_in[6];
    const float* gamma   = (const float*)d_in[7];
    const float* beta    = (const float*)d_in[8];
    const float* sk_Win  = (const float*)d_in[9];
    const float* sk_bin  = (const float*)d_in[10];
    const float* sk_Wout = (const float*)d_in[11];
    const float* sk_bout = (const float*)d_in[12];
    const float* fc1_W   = (const float*)d_in[13];
    const float* fc1_b   = (const float*)d_in[14];
    const float* fc3_W   = (const float*)d_in[15];
    const float* fc3_b   = (const float*)d_in[16];
    float* out = (float*)d_out;
    const int* ei0 = ei;
    const int* ei1 = ei + N_EDGES;

    float* ws = (float*)d_ws;
    size_t o = 0;
    unsigned short* hfullb = (unsigned short*)(ws + o); o += (size_t)N_NODES * 256;  // bf16 [N,512]
    float* gbuf   = ws + o; o += (size_t)N_NODES * 128;
    short* hbA    = (short*)(ws + o); o += (size_t)N_NODES * 64;   // bf16 [N,128] ping
    short* hbB    = (short*)(ws + o); o += (size_t)N_NODES * 64;   // pong
    float* als    = ws + o; o += N_NODES * 4;
    float* ald    = ws + o; o += N_NODES * 4;
    float* bnsum  = ws + o; o += 768;      // 3 layers x (128 sum + 128 sumsq)
    short* wt_hi   = (short*)(ws + o); o += 98304;   // 3*512*128 shorts
    short* wint_hi = (short*)(ws + o); o += 24576;   // 3*128*128 shorts
    short* woutt_hi = (short*)(ws + o); o += 24576;
    int* gstart   = (int*)(ws + o); o += 132;
    int* deg      = (int*)(ws + o); o += N_NODES;
    int* rowptr   = (int*)(ws + o); o += N_NODES + 4;
    int* wofs     = (int*)(ws + o); o += N_NODES;
    int* scantmp  = (int*)(ws + o); o += N_NODES;
    int* blksum   = (int*)(ws + o); o += NBLK + 2;
    int* blkoff   = (int*)(ws + o); o += NBLK + 2;
    int* wstart   = (int*)(ws + o); o += NWAVES + 2;
    int* csr_src  = (int*)(ws + o); o += ETOT;

    prep_kernel<<<3148, 256, 0, stream>>>(W, sk_Win, sk_Wout, x, batch,
                                          wt_hi, wint_hi, woutt_hi, hbA, gstart, deg, bnsum);

    deg_kernel<<<(ETOT + 255) / 256, 256, 0, stream>>>(ei1, deg);
    scan1<<<NBLK, 256, 0, stream>>>(deg, scantmp, blksum);
    scan2<<<1, 128, 0, stream>>>(blksum, blkoff);
    scan3<<<NBLK, 256, 0, stream>>>(scantmp, blkoff, rowptr, wofs);
    wpart_kernel<<<17, 256, 0, stream>>>(rowptr, wstart);
    scatter_kernel<<<(ETOT + 255) / 256, 256, 0, stream>>>(ei0, ei1, wofs, csr_src);

    // layer 0 conv
    gemm_conv<<<dim3(469, 4), 256, 0, stream>>>(hbA, wt_hi, att_src, att_dst, hfullb, als, ald);
    gat_gather<<<1024, 256, 0, stream>>>(rowptr, wstart, csr_src, als, ald, hfullb,
                                         conv_b, gbuf, bnsum, bnsum + 128);
    // fused skip(0) + conv(1)
    skip_conv<<<469, 256, 0, stream>>>(hbA, gbuf, bnsum, gamma, beta,
                                       wint_hi, woutt_hi, sk_bin, sk_bout,
                                       wt_hi + 65536, att_src + 512, att_dst + 512,
                                       hbB, hfullb, als, ald);
    gat_gather<<<1024, 256, 0, stream>>>(rowptr, wstart, csr_src, als, ald, hfullb,
                                         conv_b + 128, gbuf, bnsum + 256, bnsum + 384);
    // fused skip(1) + conv(2)
    skip_conv<<<469, 256, 0, stream>>>(hbB, gbuf, bnsum + 256, gamma + 128, beta + 128,
                                       wint_hi + 16384, woutt_hi + 16384, sk_bin + 128, sk_bout + 128,
                                       wt_hi + 131072, att_src + 1024, att_dst + 1024,
                                       hbA, hfullb, als, ald);
    gat_gather<<<1024, 256, 0, stream>>>(rowptr, wstart, csr_src, als, ald, hfullb,
                                         conv_b + 256, gbuf, bnsum + 512, bnsum + 640);
    // last skip
    skip_gate<<<dim3(469, 2), 256, 0, stream>>>(hbA, gbuf, bnsum + 512, gamma + 256, beta + 256,
                                                wint_hi + 32768, woutt_hi + 32768,
                                                sk_bin + 256, sk_bout + 256, hbB);

    pool_head<<<NGRAPH, 1024, 0, stream>>>(hbB, gstart, fc1_W, fc1_b, fc3_W, fc3_b, out);
}